// Round 11
// baseline (748.911 us; speedup 1.0000x reference)
//
#include <hip/hip_runtime.h>
#include <stdint.h>

typedef unsigned short ushort_t;
typedef __attribute__((ext_vector_type(4))) float f32x4;
typedef __attribute__((ext_vector_type(2))) float f32x2;
typedef __attribute__((ext_vector_type(8))) __bf16 bf16x8;
typedef __attribute__((ext_vector_type(4))) unsigned short u16x4;
typedef __attribute__((ext_vector_type(8))) unsigned short u16x8;

#define DEV __device__ __forceinline__

// async global->LDS, 16B per lane. HW: dest = wave-uniform base + laneID*16.
DEV void gload_lds16(const void* g, void* l) {
  __builtin_amdgcn_global_load_lds(
      (const __attribute__((address_space(1))) uint32_t*)(uintptr_t)(g),
      (__attribute__((address_space(3))) uint32_t*)(uintptr_t)(l), 16, 0, 0);
}

DEV ushort_t f2bf(float f) {
  union { float f; uint32_t u; } x; x.f = f;
  x.u += 0x7fffu + ((x.u >> 16) & 1u);   // RNE
  return (ushort_t)(x.u >> 16);
}

DEV float bf2f(ushort_t u) {
  union { uint32_t u; float f; } x; x.u = (uint32_t)u << 16; return x.f;
}

DEV float siluf(float x) { return x / (1.f + expf(-x)); }

#define BAR asm volatile("s_barrier" ::: "memory")
#define LGKM0 do { asm volatile("s_waitcnt lgkmcnt(0)" ::: "memory"); \
                   __builtin_amdgcn_sched_barrier(0); } while (0)
#define VMCNT(n) asm volatile("s_waitcnt vmcnt(" #n ")" ::: "memory")

// ---------------- sentinel fill (diagnostic) ----------------------------------
__global__ __launch_bounds__(256) void fill_kernel(float* p, float v, int n) {
  int i = blockIdx.x * 256 + threadIdx.x;
  if (i < n) p[i] = v;
}

// ---------------- f32 -> bf16 convert (with zero tail padding) ---------------
__global__ __launch_bounds__(256) void cvt_bf16_kernel(const float* __restrict__ src,
                                                       ushort_t* __restrict__ dst,
                                                       int n_src4, int n_dst4) {
  int i = blockIdx.x * 256 + threadIdx.x;
  if (i >= n_dst4) return;
  f32x4 v;
  if (i < n_src4) v = *(const f32x4*)(src + (size_t)i * 4);
  else { v.x = 0.f; v.y = 0.f; v.z = 0.f; v.w = 0.f; }
  u16x4 o;
  o.x = f2bf(v.x); o.y = f2bf(v.y); o.z = f2bf(v.z); o.w = f2bf(v.w);
  *(u16x4*)(dst + (size_t)i * 4) = o;
}

// ================= 256x256 8-phase bf16 GEMM (T2+T3+T4+T5) ====================
// R11: swizzle REVERTED (R10: natural dispatch gives XCD=bm%8 -> 2 A-tiles/XCD
// L2-resident; chunked swizzle broke that, FETCH 250->307MB). Kept: no ld_b2
// at P4/P8 (bf live from P1/P5).
DEV void ld_a4(const unsigned char* ab2, int mgofs, int ck0, int ck1, bf16x8 (&af)[4][2]) {
#pragma unroll
  for (int mi = 0; mi < 4; ++mi) {
    const unsigned char* p = ab2 + (mgofs + mi * 16) * 128;
    af[mi][0] = *(const bf16x8*)(p + ck0);
    af[mi][1] = *(const bf16x8*)(p + ck1);
  }
}

DEV void ld_b2(const unsigned char* bb2, int npofs, int ck0, int ck1, bf16x8 (&bf)[2][2]) {
#pragma unroll
  for (int ni = 0; ni < 2; ++ni) {
    const unsigned char* p = bb2 + (npofs + ni * 16) * 128;
    bf[ni][0] = *(const bf16x8*)(p + ck0);
    bf[ni][1] = *(const bf16x8*)(p + ck1);
  }
}

DEV void mm16(f32x4 (&acc)[8][4], const bf16x8 (&af)[4][2], const bf16x8 (&bf)[2][2],
              int mb, int nb) {
  __builtin_amdgcn_s_setprio(1);
#pragma unroll
  for (int mi = 0; mi < 4; ++mi)
#pragma unroll
    for (int ni = 0; ni < 2; ++ni)
#pragma unroll
      for (int kk = 0; kk < 2; ++kk)
        acc[mb + mi][nb + ni] = __builtin_amdgcn_mfma_f32_16x16x32_bf16(
            af[mi][kk], bf[ni][kk], acc[mb + mi][nb + ni], 0, 0, 0);
  __builtin_amdgcn_s_setprio(0);
}

DEV void stage2(const ushort_t* s0, const ushort_t* s1, unsigned char* d) {
  gload_lds16(s0, d);
  gload_lds16(s1, d + 8192);
}

template <int MODE>
__global__ __launch_bounds__(512, 1) void gemm8_kernel(const ushort_t* __restrict__ A,
                                                       const ushort_t* __restrict__ B,
                                                       void* __restrict__ C0,
                                                       void* __restrict__ C1,
                                                       int K, int NB, int NC, int niter) {
  __shared__ __align__(16) unsigned char lds[131072];
  const int tid = threadIdx.x;
  const int l = tid & 63, w = tid >> 6;
  const int wr = w >> 2, wc = w & 3;
  const int lr = l & 15, lk = l >> 4;
  const int xm = (lr & 7) << 4;
  const int ck0 = (lk * 16) ^ xm;
  const int ck1 = (64 + lk * 16) ^ xm;
  const int bm = blockIdx.x, bn = blockIdx.y;

  const int rr = (w << 3) + (l >> 3);
  const int cE = ((l & 7) ^ (l >> 3)) << 3;
  const int dstoff = w * 1024 + l * 16;

  const ushort_t* sA00 = A + (size_t)(bm * 256 +       rr) * K + cE;
  const ushort_t* sA01 = A + (size_t)(bm * 256 +  64 + rr) * K + cE;
  const ushort_t* sA10 = A + (size_t)(bm * 256 + 128 + rr) * K + cE;
  const ushort_t* sA11 = A + (size_t)(bm * 256 + 192 + rr) * K + cE;
  int rb0 = bn * 256 +       rr; if (rb0 > NB - 1) rb0 = NB - 1;
  int rb1 = bn * 256 +  64 + rr; if (rb1 > NB - 1) rb1 = NB - 1;
  int rb2 = bn * 256 + 128 + rr; if (rb2 > NB - 1) rb2 = NB - 1;
  int rb3 = bn * 256 + 192 + rr; if (rb3 > NB - 1) rb3 = NB - 1;
  const ushort_t* sB00 = B + (size_t)rb0 * K + cE;
  const ushort_t* sB01 = B + (size_t)rb1 * K + cE;
  const ushort_t* sB10 = B + (size_t)rb2 * K + cE;
  const ushort_t* sB11 = B + (size_t)rb3 * K + cE;

  const int aoff = wr * 16384 + lr * 128;
  const int boff = 32768 + (wc >> 1) * 16384 + ((wc & 1) * 64 + lr) * 128;

  f32x4 acc[8][4] = {};
  bf16x8 af[4][2], bf[2][2], bg[2][2];

  stage2(sA00, sA01, lds + dstoff);
  stage2(sA10, sA11, lds + 16384 + dstoff);
  stage2(sB00, sB01, lds + 32768 + dstoff);
  stage2(sB10, sB11, lds + 49152 + dstoff);
  stage2(sA00 + 64, sA01 + 64, lds + 65536 + dstoff);
  VMCNT(2);
  BAR;

  auto kpair = [&](int kt0, bool last) {
    const unsigned char* a0 = lds + aoff;
    const unsigned char* b0 = lds + boff;
    const unsigned char* a1 = lds + 65536 + aoff;
    const unsigned char* b1 = lds + 65536 + boff;
    const size_t c1 = (size_t)(kt0 + 1) * 64;
    const size_t c2 = (size_t)(kt0 + 2) * 64;
    const size_t c3 = (size_t)(kt0 + 3) * 64;
    ld_a4(a0, 0, ck0, ck1, af);
    ld_b2(b0, 0, ck0, ck1, bf);
    stage2(sA10 + c1, sA11 + c1, lds + 65536 + 16384 + dstoff);
    BAR; LGKM0; mm16(acc, af, bf, 0, 0); BAR;
    ld_b2(b0, 32, ck0, ck1, bg);
    stage2(sB00 + c1, sB01 + c1, lds + 65536 + 32768 + dstoff);
    BAR; LGKM0; mm16(acc, af, bg, 0, 2); BAR;
    ld_a4(a0, 64, ck0, ck1, af);
    stage2(sB10 + c1, sB11 + c1, lds + 65536 + 49152 + dstoff);
    BAR; LGKM0; mm16(acc, af, bg, 4, 2); BAR;
    if (!last) { stage2(sA00 + c2, sA01 + c2, lds + dstoff); VMCNT(2); }
    else       { VMCNT(0); }
    BAR; LGKM0; mm16(acc, af, bf, 4, 0); BAR;
    ld_a4(a1, 0, ck0, ck1, af);
    ld_b2(b1, 0, ck0, ck1, bf);
    if (!last) stage2(sA10 + c2, sA11 + c2, lds + 16384 + dstoff);
    BAR; LGKM0; mm16(acc, af, bf, 0, 0); BAR;
    ld_b2(b1, 32, ck0, ck1, bg);
    if (!last) stage2(sB00 + c2, sB01 + c2, lds + 32768 + dstoff);
    BAR; LGKM0; mm16(acc, af, bg, 0, 2); BAR;
    ld_a4(a1, 64, ck0, ck1, af);
    if (!last) stage2(sB10 + c2, sB11 + c2, lds + 49152 + dstoff);
    BAR; LGKM0; mm16(acc, af, bg, 4, 2); BAR;
    if (!last) { stage2(sA00 + c3, sA01 + c3, lds + 65536 + dstoff); VMCNT(2); }
    BAR; LGKM0; mm16(acc, af, bf, 4, 0); BAR;
  };

  for (int it = 0; it < niter - 1; ++it) kpair(2 * it, false);
  kpair(2 * (niter - 1), true);

  const int crow0 = bm * 256 + wr * 128 + (lk << 2);
  const int ccol0 = bn * 256 + wc * 64 + lr;
  if (MODE == 0) {
    ushort_t* gate = (ushort_t*)C0;
    ushort_t* xbc  = (ushort_t*)C1;
#pragma unroll
    for (int ni = 0; ni < 4; ++ni) {
      const int col = ccol0 + ni * 16;
      if (col < NC) {
        ushort_t* dst; size_t stride;
        if (col < 4096) { dst = gate + col; stride = 4096; }
        else            { dst = xbc + (col - 4096); stride = 6272; }
#pragma unroll
        for (int mi = 0; mi < 8; ++mi)
#pragma unroll
          for (int r = 0; r < 4; ++r)
            dst[(size_t)(crow0 + mi * 16 + r) * stride] = f2bf(acc[mi][ni][r]);
      }
    }
  } else {
    float* o = (float*)C0;
#pragma unroll
    for (int ni = 0; ni < 4; ++ni) {
      const int col = ccol0 + ni * 16;
      if (col < NC) {
#pragma unroll
        for (int mi = 0; mi < 8; ++mi)
#pragma unroll
          for (int r = 0; r < 4; ++r)
            o[(size_t)(crow0 + mi * 16 + r) * NC + col] = acc[mi][ni][r];
      }
    }
  }
}

// ---------------- causal depthwise conv (K=4) + bias + SiLU, bf16 in/out ------
__global__ __launch_bounds__(256) void conv_silu_kernel(const ushort_t* __restrict__ xbc,
                                                        const float* __restrict__ cw,
                                                        const float* __restrict__ cb,
                                                        ushort_t* __restrict__ out) {
  int idx = blockIdx.x * 256 + threadIdx.x;      // 4096*1536
  int c4 = (idx % 1536) << 2;
  int bt = idx / 1536;
  int t = bt & 2047;
  const ushort_t* base = xbc + (size_t)bt * 6272 + c4;
  f32x4 w0 = *(const f32x4*)&cw[(c4 + 0) * 4];
  f32x4 w1 = *(const f32x4*)&cw[(c4 + 1) * 4];
  f32x4 w2 = *(const f32x4*)&cw[(c4 + 2) * 4];
  f32x4 w3 = *(const f32x4*)&cw[(c4 + 3) * 4];
  f32x4 acc = *(const f32x4*)&cb[c4];
#pragma unroll
  for (int i = 0; i < 4; ++i) {
    int dt_ = i - 3;
    if (t + dt_ >= 0) {
      u16x4 xv = *(const u16x4*)(base + (ptrdiff_t)dt_ * 6272);
      acc.x += bf2f(xv.x) * w0[i];
      acc.y += bf2f(xv.y) * w1[i];
      acc.z += bf2f(xv.z) * w2[i];
      acc.w += bf2f(xv.w) * w3[i];
    }
  }
  u16x4 o;
  o.x = f2bf(siluf(acc.x)); o.y = f2bf(siluf(acc.y));
  o.z = f2bf(siluf(acc.z)); o.w = f2bf(siluf(acc.w));
  *(u16x4*)(out + (size_t)bt * 6144 + c4) = o;
}

// ---------------- dt: softplus + exp(A*dt), layout [H][2][BT] f32 -------------
__global__ __launch_bounds__(256) void dt_kernel(const ushort_t* __restrict__ xbc,
                                                 const float* __restrict__ dt_bias,
                                                 const float* __restrict__ Avec,
                                                 float* __restrict__ dtA) {
  int idx = blockIdx.x * 256 + threadIdx.x;      // 64*4096
  int h = idx >> 12, bt = idx & 4095;
  float v = bf2f(xbc[(size_t)bt * 6272 + 6144 + h]) + dt_bias[h];
  float sp = fmaxf(v, 0.f) + log1pf(expf(-fabsf(v)));
  float ab = expf(Avec[h] * sp);
  dtA[(h << 13) + bt] = sp;
  dtA[(h << 13) + 4096 + bt] = ab;
}

// ---------------- SSD chunk kernel (replaces sequential scan) -----------------
// grid 1024 = b(2) x h(64) x ck(8); 256 thr = 4 waves. Per chunk (256 steps):
//  cs = cumsum(dt); w_t = dt_t*exp(A(cs_T-cs_t))
//  hst[p][n] = sum_t XT[p][t] * (w_t B[t][n])          (MFMA, BTw chunks)
//  S[i][j]  = sum_n C[i][n] B[j][n]                    (MFMA, global frags)
//  P[i][j]  = S * dt_j * exp(A(cs_i-cs_j)) * 1[j<=i]   (mask -> swizzled LDS)
//  Y^T[p][i]= sum_j XT[p][j] P[i][j]; y += D*x         (MFMA)
// Inter-chunk term added later by correct_kernel (unchanged).
// XOR swizzle on XT/P rows: byte ^= (row&7)<<4 (write==read, T2/G4).
__global__ __launch_bounds__(256) void ssd_kernel(const ushort_t* __restrict__ conv,
                                                  const float* __restrict__ dtA,
                                                  const float* __restrict__ Dvec,
                                                  const float* __restrict__ Avec,
                                                  ushort_t* __restrict__ yssm,
                                                  ushort_t* __restrict__ hst,
                                                  float* __restrict__ abprod) {
  const int bid = blockIdx.x;
  const int ck = bid & 7;
  const int h = (bid >> 3) & 63;
  const int b = bid >> 9;
  const int g = h >> 3;
  const int tid = threadIdx.x;
  const int lane = tid & 63;
  const int wv = tid >> 6;
  const int lr = lane & 15, lk = lane >> 4;
  const int btb = (b << 11) + (ck << 8);

  // LDS: XT[64][256]bf16 @0 (32K) | P[64][256]bf16 @32768 (32K) |
  //      BTc[128][32]bf16 @65536 (8K) | cs f32[256] @73728 | dt @74752 |
  //      w @75776 | wsum @76800
  __shared__ __align__(16) unsigned char ldsb[76816];
  float* csL = (float*)(ldsb + 73728);
  float* dtL = (float*)(ldsb + 74752);
  float* wL  = (float*)(ldsb + 75776);
  float* wsum = (float*)(ldsb + 76800);

  const float Ah = Avec[h];
  const float Dh = Dvec[h];

  // ---- Ph0: inclusive cumsum of dt (verified pattern from correct_kernel) ----
  float dv = dtA[(h << 13) + btb + tid];
  float s = dv;
#pragma unroll
  for (int off = 1; off < 64; off <<= 1) {
    float t = __shfl_up(s, off, 64);
    if (lane >= off) s += t;
  }
  if (lane == 63) wsum[wv] = s;
  __syncthreads();
  float basev = 0.f;
  for (int i = 0; i < wv; ++i) basev += wsum[i];
  const float csv = basev + s;
  csL[tid] = csv;
  dtL[tid] = dv;
  __syncthreads();
  const float cstot = csL[255];
  wL[tid] = dv * expf(Ah * (cstot - csv));
  if (tid == 0) abprod[((b << 6) + h) * 8 + ck] = expf(Ah * cstot);

  // ---- Ph1: build XT[p][t] (swizzled) from conv x block -----------------------
  const ushort_t* Xg = conv + (size_t)btb * 6144 + (h << 6);
#pragma unroll
  for (int rep = 0; rep < 8; ++rep) {
    int idx = rep * 256 + tid;           // 0..2047 vec8 chunks
    int t = idx >> 3, pq = (idx & 7) << 3;
    u16x8 v = *(const u16x8*)(Xg + (size_t)t * 6144 + pq);
#pragma unroll
    for (int e = 0; e < 8; ++e) {
      int p = pq + e;
      *(ushort_t*)(ldsb + p * 512 + ((t * 2) ^ ((p & 7) << 4))) = v[e];
    }
  }
  __syncthreads();

  // ---- Ph2: hst = XT * BTw^T, BTw built in 32-t chunks ------------------------
  const ushort_t* Bg = conv + (size_t)btb * 6144 + 4096 + (g << 7);
  f32x4 hacc[4][2] = {};
  for (int tc = 0; tc < 8; ++tc) {
#pragma unroll
    for (int rep = 0; rep < 2; ++rep) {
      int idx = rep * 256 + tid;         // 0..511 vec8 chunks
      int tl = idx >> 4, nq = (idx & 15) << 3;
      u16x8 v = *(const u16x8*)(Bg + (size_t)(tc * 32 + tl) * 6144 + nq);
      float wt = wL[tc * 32 + tl];
#pragma unroll
      for (int e = 0; e < 8; ++e) {
        int n = nq + e;
        *(ushort_t*)(ldsb + 65536 + n * 64 + ((tl * 2) ^ ((n & 3) << 4))) =
            f2bf(bf2f(v[e]) * wt);
      }
    }
    __syncthreads();
    bf16x8 a4[4], b2[2];
#pragma unroll
    for (int pf = 0; pf < 4; ++pf) {
      int p = pf * 16 + lr;
      a4[pf] = *(const bf16x8*)(ldsb + p * 512 + (((tc * 32 + lk * 8) * 2) ^ ((p & 7) << 4)));
    }
#pragma unroll
    for (int nf = 0; nf < 2; ++nf) {
      int n = wv * 32 + nf * 16 + lr;
      b2[nf] = *(const bf16x8*)(ldsb + 65536 + n * 64 + ((lk * 16) ^ ((n & 3) << 4)));
    }
#pragma unroll
    for (int pf = 0; pf < 4; ++pf)
#pragma unroll
      for (int nf = 0; nf < 2; ++nf)
        hacc[pf][nf] = __builtin_amdgcn_mfma_f32_16x16x32_bf16(a4[pf], b2[nf],
                                                               hacc[pf][nf], 0, 0, 0);
    __syncthreads();
  }
  // write hst (layout identical to prior rounds: combine/correct unchanged)
#pragma unroll
  for (int pf = 0; pf < 4; ++pf)
#pragma unroll
    for (int nf = 0; nf < 2; ++nf)
#pragma unroll
      for (int r = 0; r < 4; ++r) {
        int p = pf * 16 + (lk << 2) + r;
        int n = wv * 32 + nf * 16 + lr;
        hst[((size_t)((b << 10) | (h << 4) | ((p >> 5) << 3) | ck)) * 4096 +
            (size_t)(p & 31) * 128 + n] = f2bf(hacc[pf][nf][r]);
      }

  // ---- Ph3: per 64-row block: S -> mask -> P -> Y^T ---------------------------
  const ushort_t* Cg = conv + (size_t)btb * 6144 + 5120 + (g << 7);
  for (int rb = 0; rb < 4; ++rb) {
    const int i0 = rb << 6;
    f32x4 sacc[4][4] = {};
#pragma unroll
    for (int kk = 0; kk < 4; ++kk) {
      bf16x8 ca[4], bb[4];
#pragma unroll
      for (int ifr = 0; ifr < 4; ++ifr)
        ca[ifr] = *(const bf16x8*)(Cg + (size_t)(i0 + ifr * 16 + lr) * 6144 + kk * 32 + lk * 8);
#pragma unroll
      for (int jf = 0; jf < 4; ++jf)
        bb[jf] = *(const bf16x8*)(Bg + (size_t)(wv * 64 + jf * 16 + lr) * 6144 + kk * 32 + lk * 8);
#pragma unroll
      for (int ifr = 0; ifr < 4; ++ifr)
#pragma unroll
        for (int jf = 0; jf < 4; ++jf)
          sacc[ifr][jf] = __builtin_amdgcn_mfma_f32_16x16x32_bf16(ca[ifr], bb[jf],
                                                                  sacc[ifr][jf], 0, 0, 0);
    }
    // mask + write P (swizzled)
#pragma unroll
    for (int ifr = 0; ifr < 4; ++ifr) {
#pragma unroll
      for (int jf = 0; jf < 4; ++jf) {
        int j = wv * 64 + jf * 16 + lr;
        float dtj = dtL[j], csj = csL[j];
#pragma unroll
        for (int r = 0; r < 4; ++r) {
          int il = ifr * 16 + (lk << 2) + r;
          int ig = i0 + il;
          float val = 0.f;
          if (j <= ig) val = sacc[ifr][jf][r] * dtj * expf(Ah * (csL[ig] - csj));
          *(ushort_t*)(ldsb + 32768 + il * 512 + ((j * 2) ^ ((il & 7) << 4))) = f2bf(val);
        }
      }
    }
    __syncthreads();
    // Y^T[p][i] = sum_j XT[p][j] * P[i][j]; wave owns i-quarter
    f32x4 yacc[4] = {};
    const int ilB = wv * 16 + lr;
#pragma unroll
    for (int ks = 0; ks < 8; ++ks) {
      bf16x8 pb = *(const bf16x8*)(ldsb + 32768 + ilB * 512 +
                                   (((ks * 32 + lk * 8) * 2) ^ ((ilB & 7) << 4)));
#pragma unroll
      for (int pf = 0; pf < 4; ++pf) {
        int p = pf * 16 + lr;
        bf16x8 pa = *(const bf16x8*)(ldsb + p * 512 +
                                     (((ks * 32 + lk * 8) * 2) ^ ((p & 7) << 4)));
        yacc[pf] = __builtin_amdgcn_mfma_f32_16x16x32_bf16(pa, pb, yacc[pf], 0, 0, 0);
      }
    }
    // epilogue: + D*x, write yssm (col = i = wv*16+lr, rows p)
    const int irow = i0 + wv * 16 + lr;
    const size_t ybase = (size_t)(btb + irow) * 4096 + (h << 6);
#pragma unroll
    for (int pf = 0; pf < 4; ++pf) {
      u16x4 o;
#pragma unroll
      for (int r = 0; r < 4; ++r) {
        int p = pf * 16 + (lk << 2) + r;
        float xv = bf2f(*(const ushort_t*)(ldsb + p * 512 +
                                           ((irow * 2) ^ ((p & 7) << 4))));
        o[r] = f2bf(yacc[pf][r] + Dh * xv);
      }
      *(u16x4*)(yssm + ybase + pf * 16 + (lk << 2)) = o;
    }
    __syncthreads();   // protect P before next rb overwrites it
  }
}

// ---------------- combine: prefix over chunk states (in place) ----------------
__global__ __launch_bounds__(256) void combine_kernel(ushort_t* __restrict__ hst,
                                                      const float* __restrict__ abprod) {
  const int bid = blockIdx.x;
  const int bh = bid >> 1;
  const int tid = threadIdx.x;
  const size_t base = (size_t)bid * 8 * 4096 + tid * 16;
  float hrun[16];
#pragma unroll
  for (int e = 0; e < 16; ++e) hrun[e] = 0.f;
  for (int c = 0; c < 8; ++c) {
    const size_t p = base + (size_t)c * 4096;
    u16x8 v0 = *(const u16x8*)&hst[p];
    u16x8 v1 = *(const u16x8*)&hst[p + 8];
    float ab = abprod[bh * 8 + c];
    u16x8 w0, w1;
#pragma unroll
    for (int e = 0; e < 8; ++e) { w0[e] = f2bf(hrun[e]); w1[e] = f2bf(hrun[8 + e]); }
    *(u16x8*)&hst[p] = w0;
    *(u16x8*)&hst[p + 8] = w1;
#pragma unroll
    for (int e = 0; e < 8; ++e) {
      hrun[e] = ab * hrun[e] + bf2f(v0[e]);
      hrun[8 + e] = ab * hrun[8 + e] + bf2f(v1[e]);
    }
  }
}

// ---------------- correction: yssm += pd[t] * (C_t . H_init) ------------------
__global__ __launch_bounds__(256) void correct_kernel(const ushort_t* __restrict__ conv,
                                                      const float* __restrict__ dtA,
                                                      const float* __restrict__ Avec,
                                                      const ushort_t* __restrict__ hst,
                                                      ushort_t* __restrict__ yssm) {
  const int bid = blockIdx.x;
  const int ck = bid & 7;
  const int h = (bid >> 3) & 63;
  const int b = bid >> 9;
  const int g = h >> 3;
  const int tid = threadIdx.x;
  const int lane = tid & 63;
  const int w = tid >> 6;
  const int lr = lane & 15, lk = lane >> 4;
  const int btb = (b << 11) + (ck << 8);

  __shared__ float pdl[256];
  __shared__ float wsum[4];
  float s = dtA[(h << 13) + btb + tid];
#pragma unroll
  for (int off = 1; off < 64; off <<= 1) {
    float t = __shfl_up(s, off, 64);
    if (lane >= off) s += t;
  }
  if (lane == 63) wsum[w] = s;
  __syncthreads();
  float basev = 0.f;
  for (int i = 0; i < w; ++i) basev += wsum[i];
  pdl[tid] = expf(Avec[h] * (basev + s));
  __syncthreads();

  const ushort_t* Cc = conv + (size_t)btb * 6144 + 5120 + (g << 7);
  const size_t hb0 = ((size_t)((b << 10) | (h << 4) | (0 << 3) | ck)) * 4096;
  const size_t hb1 = ((size_t)((b << 10) | (h << 4) | (1 << 3) | ck)) * 4096;

  f32x4 acc[4][4] = {};
#pragma unroll
  for (int kk = 0; kk < 4; ++kk) {
    const int k0 = kk * 32 + lk * 8;
    bf16x8 afr[4], bfr[4];
#pragma unroll
    for (int mf = 0; mf < 4; ++mf) {
      const int t = w * 64 + mf * 16 + lr;
      afr[mf] = *(const bf16x8*)(Cc + (size_t)t * 6144 + k0);
    }
#pragma unroll
    for (int nf = 0; nf < 4; ++nf) {
      const int p = nf * 16 + lr;
      const size_t hb = (p < 32) ? hb0 : hb1;
      bfr[nf] = *(const bf16x8*)(hst + hb + (size_t)(p & 31) * 128 + k0);
    }
#pragma unroll
    for (int mf = 0; mf < 4; ++mf)
#pragma unroll
      for (int nf = 0; nf < 4; ++nf)
        acc[mf][nf] = __builtin_amdgcn_mfma_f32_16x16x32_bf16(afr[mf], bfr[nf],
                                                              acc[mf][nf], 0, 0, 0);
  }

#pragma unroll
  for (int mf = 0; mf < 4; ++mf) {
#pragma unroll
    for (int r = 0; r < 4; ++r) {
      const int row = w * 64 + mf * 16 + (lk << 2) + r;
      const float pd = pdl[row];
      const size_t yrow = (size_t)(btb + row) * 4096 + (h << 6);
#pragma unroll
      for (int nf = 0; nf < 4; ++nf) {
        const int p = nf * 16 + lr;
        const size_t idx = yrow + p;
        yssm[idx] = f2bf(bf2f(yssm[idx]) + pd * acc[mf][nf][r]);
      }
    }
  }
}

// ---------------- gate * silu + RMSNorm -> bf16 -------------------------------
__global__ __launch_bounds__(256) void norm_kernel(const ushort_t* __restrict__ yssm,
                                                   const ushort_t* __restrict__ gate,
                                                   const float* __restrict__ nw,
                                                   ushort_t* __restrict__ out) {
  const int bt = blockIdx.x;
  const int tid = threadIdx.x;
  const ushort_t* y = yssm + (size_t)bt * 4096;
  const ushort_t* gt = gate + (size_t)bt * 4096;
  float vals[16];
  float ss = 0.f;
#pragma unroll
  for (int j = 0; j < 4; ++j) {
    int o = (tid + j * 256) << 2;
    u16x4 yv = *(const u16x4*)(y + o);
    u16x4 gv = *(const u16x4*)(gt + o);
#pragma unroll
    for (int e = 0; e < 4; ++e) {
      float v = bf2f(yv[e]) * siluf(bf2f(gv[e]));
      vals[j * 4 + e] = v;
      ss += v * v;
    }
  }
#pragma unroll
  for (int m = 1; m <= 32; m <<= 1) ss += __shfl_xor(ss, m, 64);
  __shared__ float red[4];
  if ((tid & 63) == 0) red[tid >> 6] = ss;
  __syncthreads();
  ss = red[0] + red[1] + red[2] + red[3];
  const float sc = rsqrtf(ss * (1.f / 4096.f) + 1e-5f);
#pragma unroll
  for (int j = 0; j < 4; ++j) {
    int o = (tid + j * 256) << 2;
    f32x4 wv = *(const f32x4*)(nw + o);
    u16x4 ov;
    ov.x = f2bf(vals[j * 4 + 0] * sc * wv.x);
    ov.y = f2bf(vals[j * 4 + 1] * sc * wv.y);
    ov.z = f2bf(vals[j * 4 + 2] * sc * wv.z);
    ov.w = f2bf(vals[j * 4 + 3] * sc * wv.w);
    *(u16x4*)(out + (size_t)bt * 4096 + o) = ov;
  }
}

// ------------------------------------------------------------------------------
extern "C" void kernel_launch(void* const* d_in, const int* in_sizes, int n_in,
                              void* d_out, int out_size, void* d_ws, size_t ws_size,
                              hipStream_t stream) {
  const float* hidden  = (const float*)d_in[0];
  const float* w_in    = (const float*)d_in[1];
  const float* conv_w  = (const float*)d_in[2];
  const float* conv_b  = (const float*)d_in[3];
  const float* Avec    = (const float*)d_in[4];
  const float* Dvec    = (const float*)d_in[5];
  const float* dt_bias = (const float*)d_in[6];
  const float* nw      = (const float*)d_in[7];
  const float* w_out   = (const float*)d_in[8];
  float* out = (float*)d_out;

  char* ws = (char*)d_ws;
  // Region map (total 162,693,120 B) — unchanged since R4.
  ushort_t* Xbf   = (ushort_t*)(ws);
  ushort_t* W1bf  = (ushort_t*)(ws + 22020096);
  ushort_t* gate  = (ushort_t*)(ws + 77758464);
  ushort_t* xbc   = (ushort_t*)(ws + 111312896);
  ushort_t* W2bf  = Xbf;
  ushort_t* convb = W1bf;
  float*    dtA   = (float*)(ws + 22020096 + 50331648);
  float*    abprod= (float*)(ws + 22020096 + 52428800);
  ushort_t* yssm  = xbc;
  ushort_t* hst   = (ushort_t*)(ws + 111312896 + 33554432);
  ushort_t* ynorm = convb;
  const size_t NEED = 162693120;
  if (NEED > ws_size) {
    fill_kernel<<<4, 256, 0, stream>>>(out, 12345.0f, 1024);   // sentinel: ws too small
    return;
  }

  cvt_bf16_kernel<<<10752, 256, 0, stream>>>(hidden, Xbf, 2752512, 2752512);
  cvt_bf16_kernel<<<27216, 256, 0, stream>>>(w_in, W1bf, 6924288, 6967296);
  gemm8_kernel<0><<<dim3(16, 41), 512, 0, stream>>>(Xbf, W1bf, gate, xbc,
                                                    2688, 10368, 10304, 21);
  cvt_bf16_kernel<<<10752, 256, 0, stream>>>(w_out, W2bf, 2752512, 2752512);
  conv_silu_kernel<<<24576, 256, 0, stream>>>(xbc, conv_w, conv_b, convb);
  dt_kernel<<<1024, 256, 0, stream>>>(xbc, dt_bias, Avec, dtA);
  ssd_kernel<<<1024, 256, 0, stream>>>(convb, dtA, Dvec, Avec, yssm, hst, abprod);
  combine_kernel<<<256, 256, 0, stream>>>(hst, abprod);
  correct_kernel<<<1024, 256, 0, stream>>>(convb, dtA, Avec, hst, yssm);
  norm_kernel<<<4096, 256, 0, stream>>>(yssm, gate, nw, ynorm);
  gemm8_kernel<1><<<dim3(16, 11), 512, 0, stream>>>(ynorm, W2bf, out, nullptr,
                                                    4096, 2688, 2688, 32);
}

// Round 12
// 711.805 us; speedup vs baseline: 1.0521x; 1.0521x over previous
//
#include <hip/hip_runtime.h>
#include <stdint.h>

typedef unsigned short ushort_t;
typedef __attribute__((ext_vector_type(4))) float f32x4;
typedef __attribute__((ext_vector_type(2))) float f32x2;
typedef __attribute__((ext_vector_type(8))) __bf16 bf16x8;
typedef __attribute__((ext_vector_type(4))) unsigned short u16x4;
typedef __attribute__((ext_vector_type(8))) unsigned short u16x8;

#define DEV __device__ __forceinline__

// async global->LDS, 16B per lane. HW: dest = wave-uniform base + laneID*16.
DEV void gload_lds16(const void* g, void* l) {
  __builtin_amdgcn_global_load_lds(
      (const __attribute__((address_space(1))) uint32_t*)(uintptr_t)(g),
      (__attribute__((address_space(3))) uint32_t*)(uintptr_t)(l), 16, 0, 0);
}

DEV ushort_t f2bf(float f) {
  union { float f; uint32_t u; } x; x.f = f;
  x.u += 0x7fffu + ((x.u >> 16) & 1u);   // RNE
  return (ushort_t)(x.u >> 16);
}

DEV float bf2f(ushort_t u) {
  union { uint32_t u; float f; } x; x.u = (uint32_t)u << 16; return x.f;
}

DEV float siluf(float x) { return x / (1.f + expf(-x)); }

#define BAR asm volatile("s_barrier" ::: "memory")
#define LGKM0 do { asm volatile("s_waitcnt lgkmcnt(0)" ::: "memory"); \
                   __builtin_amdgcn_sched_barrier(0); } while (0)
#define VMCNT(n) asm volatile("s_waitcnt vmcnt(" #n ")" ::: "memory")

// ---------------- sentinel fill (diagnostic) ----------------------------------
__global__ __launch_bounds__(256) void fill_kernel(float* p, float v, int n) {
  int i = blockIdx.x * 256 + threadIdx.x;
  if (i < n) p[i] = v;
}

// ---------------- f32 -> bf16 convert (with zero tail padding) ---------------
__global__ __launch_bounds__(256) void cvt_bf16_kernel(const float* __restrict__ src,
                                                       ushort_t* __restrict__ dst,
                                                       int n_src4, int n_dst4) {
  int i = blockIdx.x * 256 + threadIdx.x;
  if (i >= n_dst4) return;
  f32x4 v;
  if (i < n_src4) v = *(const f32x4*)(src + (size_t)i * 4);
  else { v.x = 0.f; v.y = 0.f; v.z = 0.f; v.w = 0.f; }
  u16x4 o;
  o.x = f2bf(v.x); o.y = f2bf(v.y); o.z = f2bf(v.z); o.w = f2bf(v.w);
  *(u16x4*)(dst + (size_t)i * 4) = o;
}

// ================= 256x256 8-phase bf16 GEMM (T2+T3+T4+T5) ====================
// (R11 version: natural dispatch order; no redundant ld_b2 at P4/P8)
DEV void ld_a4(const unsigned char* ab2, int mgofs, int ck0, int ck1, bf16x8 (&af)[4][2]) {
#pragma unroll
  for (int mi = 0; mi < 4; ++mi) {
    const unsigned char* p = ab2 + (mgofs + mi * 16) * 128;
    af[mi][0] = *(const bf16x8*)(p + ck0);
    af[mi][1] = *(const bf16x8*)(p + ck1);
  }
}

DEV void ld_b2(const unsigned char* bb2, int npofs, int ck0, int ck1, bf16x8 (&bf)[2][2]) {
#pragma unroll
  for (int ni = 0; ni < 2; ++ni) {
    const unsigned char* p = bb2 + (npofs + ni * 16) * 128;
    bf[ni][0] = *(const bf16x8*)(p + ck0);
    bf[ni][1] = *(const bf16x8*)(p + ck1);
  }
}

DEV void mm16(f32x4 (&acc)[8][4], const bf16x8 (&af)[4][2], const bf16x8 (&bf)[2][2],
              int mb, int nb) {
  __builtin_amdgcn_s_setprio(1);
#pragma unroll
  for (int mi = 0; mi < 4; ++mi)
#pragma unroll
    for (int ni = 0; ni < 2; ++ni)
#pragma unroll
      for (int kk = 0; kk < 2; ++kk)
        acc[mb + mi][nb + ni] = __builtin_amdgcn_mfma_f32_16x16x32_bf16(
            af[mi][kk], bf[ni][kk], acc[mb + mi][nb + ni], 0, 0, 0);
  __builtin_amdgcn_s_setprio(0);
}

DEV void stage2(const ushort_t* s0, const ushort_t* s1, unsigned char* d) {
  gload_lds16(s0, d);
  gload_lds16(s1, d + 8192);
}

template <int MODE>
__global__ __launch_bounds__(512, 1) void gemm8_kernel(const ushort_t* __restrict__ A,
                                                       const ushort_t* __restrict__ B,
                                                       void* __restrict__ C0,
                                                       void* __restrict__ C1,
                                                       int K, int NB, int NC, int niter) {
  __shared__ __align__(16) unsigned char lds[131072];
  const int tid = threadIdx.x;
  const int l = tid & 63, w = tid >> 6;
  const int wr = w >> 2, wc = w & 3;
  const int lr = l & 15, lk = l >> 4;
  const int xm = (lr & 7) << 4;
  const int ck0 = (lk * 16) ^ xm;
  const int ck1 = (64 + lk * 16) ^ xm;
  const int bm = blockIdx.x, bn = blockIdx.y;

  const int rr = (w << 3) + (l >> 3);
  const int cE = ((l & 7) ^ (l >> 3)) << 3;
  const int dstoff = w * 1024 + l * 16;

  const ushort_t* sA00 = A + (size_t)(bm * 256 +       rr) * K + cE;
  const ushort_t* sA01 = A + (size_t)(bm * 256 +  64 + rr) * K + cE;
  const ushort_t* sA10 = A + (size_t)(bm * 256 + 128 + rr) * K + cE;
  const ushort_t* sA11 = A + (size_t)(bm * 256 + 192 + rr) * K + cE;
  int rb0 = bn * 256 +       rr; if (rb0 > NB - 1) rb0 = NB - 1;
  int rb1 = bn * 256 +  64 + rr; if (rb1 > NB - 1) rb1 = NB - 1;
  int rb2 = bn * 256 + 128 + rr; if (rb2 > NB - 1) rb2 = NB - 1;
  int rb3 = bn * 256 + 192 + rr; if (rb3 > NB - 1) rb3 = NB - 1;
  const ushort_t* sB00 = B + (size_t)rb0 * K + cE;
  const ushort_t* sB01 = B + (size_t)rb1 * K + cE;
  const ushort_t* sB10 = B + (size_t)rb2 * K + cE;
  const ushort_t* sB11 = B + (size_t)rb3 * K + cE;

  const int aoff = wr * 16384 + lr * 128;
  const int boff = 32768 + (wc >> 1) * 16384 + ((wc & 1) * 64 + lr) * 128;

  f32x4 acc[8][4] = {};
  bf16x8 af[4][2], bf[2][2], bg[2][2];

  stage2(sA00, sA01, lds + dstoff);
  stage2(sA10, sA11, lds + 16384 + dstoff);
  stage2(sB00, sB01, lds + 32768 + dstoff);
  stage2(sB10, sB11, lds + 49152 + dstoff);
  stage2(sA00 + 64, sA01 + 64, lds + 65536 + dstoff);
  VMCNT(2);
  BAR;

  auto kpair = [&](int kt0, bool last) {
    const unsigned char* a0 = lds + aoff;
    const unsigned char* b0 = lds + boff;
    const unsigned char* a1 = lds + 65536 + aoff;
    const unsigned char* b1 = lds + 65536 + boff;
    const size_t c1 = (size_t)(kt0 + 1) * 64;
    const size_t c2 = (size_t)(kt0 + 2) * 64;
    const size_t c3 = (size_t)(kt0 + 3) * 64;
    ld_a4(a0, 0, ck0, ck1, af);
    ld_b2(b0, 0, ck0, ck1, bf);
    stage2(sA10 + c1, sA11 + c1, lds + 65536 + 16384 + dstoff);
    BAR; LGKM0; mm16(acc, af, bf, 0, 0); BAR;
    ld_b2(b0, 32, ck0, ck1, bg);
    stage2(sB00 + c1, sB01 + c1, lds + 65536 + 32768 + dstoff);
    BAR; LGKM0; mm16(acc, af, bg, 0, 2); BAR;
    ld_a4(a0, 64, ck0, ck1, af);
    stage2(sB10 + c1, sB11 + c1, lds + 65536 + 49152 + dstoff);
    BAR; LGKM0; mm16(acc, af, bg, 4, 2); BAR;
    if (!last) { stage2(sA00 + c2, sA01 + c2, lds + dstoff); VMCNT(2); }
    else       { VMCNT(0); }
    BAR; LGKM0; mm16(acc, af, bf, 4, 0); BAR;
    ld_a4(a1, 0, ck0, ck1, af);
    ld_b2(b1, 0, ck0, ck1, bf);
    if (!last) stage2(sA10 + c2, sA11 + c2, lds + 16384 + dstoff);
    BAR; LGKM0; mm16(acc, af, bf, 0, 0); BAR;
    ld_b2(b1, 32, ck0, ck1, bg);
    if (!last) stage2(sB00 + c2, sB01 + c2, lds + 32768 + dstoff);
    BAR; LGKM0; mm16(acc, af, bg, 0, 2); BAR;
    ld_a4(a1, 64, ck0, ck1, af);
    if (!last) stage2(sB10 + c2, sB11 + c2, lds + 49152 + dstoff);
    BAR; LGKM0; mm16(acc, af, bg, 4, 2); BAR;
    if (!last) { stage2(sA00 + c3, sA01 + c3, lds + 65536 + dstoff); VMCNT(2); }
    BAR; LGKM0; mm16(acc, af, bf, 4, 0); BAR;
  };

  for (int it = 0; it < niter - 1; ++it) kpair(2 * it, false);
  kpair(2 * (niter - 1), true);

  const int crow0 = bm * 256 + wr * 128 + (lk << 2);
  const int ccol0 = bn * 256 + wc * 64 + lr;
  if (MODE == 0) {
    ushort_t* gate = (ushort_t*)C0;
    ushort_t* xbc  = (ushort_t*)C1;
#pragma unroll
    for (int ni = 0; ni < 4; ++ni) {
      const int col = ccol0 + ni * 16;
      if (col < NC) {
        ushort_t* dst; size_t stride;
        if (col < 4096) { dst = gate + col; stride = 4096; }
        else            { dst = xbc + (col - 4096); stride = 6272; }
#pragma unroll
        for (int mi = 0; mi < 8; ++mi)
#pragma unroll
          for (int r = 0; r < 4; ++r)
            dst[(size_t)(crow0 + mi * 16 + r) * stride] = f2bf(acc[mi][ni][r]);
      }
    }
  } else {
    float* o = (float*)C0;
#pragma unroll
    for (int ni = 0; ni < 4; ++ni) {
      const int col = ccol0 + ni * 16;
      if (col < NC) {
#pragma unroll
        for (int mi = 0; mi < 8; ++mi)
#pragma unroll
          for (int r = 0; r < 4; ++r)
            o[(size_t)(crow0 + mi * 16 + r) * NC + col] = acc[mi][ni][r];
      }
    }
  }
}

// ---------------- causal depthwise conv (K=4) + bias + SiLU, bf16 in/out ------
__global__ __launch_bounds__(256) void conv_silu_kernel(const ushort_t* __restrict__ xbc,
                                                        const float* __restrict__ cw,
                                                        const float* __restrict__ cb,
                                                        ushort_t* __restrict__ out) {
  int idx = blockIdx.x * 256 + threadIdx.x;      // 4096*1536
  int c4 = (idx % 1536) << 2;
  int bt = idx / 1536;
  int t = bt & 2047;
  const ushort_t* base = xbc + (size_t)bt * 6272 + c4;
  f32x4 w0 = *(const f32x4*)&cw[(c4 + 0) * 4];
  f32x4 w1 = *(const f32x4*)&cw[(c4 + 1) * 4];
  f32x4 w2 = *(const f32x4*)&cw[(c4 + 2) * 4];
  f32x4 w3 = *(const f32x4*)&cw[(c4 + 3) * 4];
  f32x4 acc = *(const f32x4*)&cb[c4];
#pragma unroll
  for (int i = 0; i < 4; ++i) {
    int dt_ = i - 3;
    if (t + dt_ >= 0) {
      u16x4 xv = *(const u16x4*)(base + (ptrdiff_t)dt_ * 6272);
      acc.x += bf2f(xv.x) * w0[i];
      acc.y += bf2f(xv.y) * w1[i];
      acc.z += bf2f(xv.z) * w2[i];
      acc.w += bf2f(xv.w) * w3[i];
    }
  }
  u16x4 o;
  o.x = f2bf(siluf(acc.x)); o.y = f2bf(siluf(acc.y));
  o.z = f2bf(siluf(acc.z)); o.w = f2bf(siluf(acc.w));
  *(u16x4*)(out + (size_t)bt * 6144 + c4) = o;
}

// ---------------- dt: softplus + exp(A*dt), layout [H][2][BT] f32 -------------
__global__ __launch_bounds__(256) void dt_kernel(const ushort_t* __restrict__ xbc,
                                                 const float* __restrict__ dt_bias,
                                                 const float* __restrict__ Avec,
                                                 float* __restrict__ dtA) {
  int idx = blockIdx.x * 256 + threadIdx.x;      // 64*4096
  int h = idx >> 12, bt = idx & 4095;
  float v = bf2f(xbc[(size_t)bt * 6272 + 6144 + h]) + dt_bias[h];
  float sp = fmaxf(v, 0.f) + log1pf(expf(-fabsf(v)));
  float ab = expf(Avec[h] * sp);
  dtA[(h << 13) + bt] = sp;
  dtA[(h << 13) + 4096 + bt] = ab;
}

// ---------------- SSD chunk kernel (R12: conflict-free data movement) ---------
// Same math as R11 (verified). Layouts:
//  XT[64p][512B] @0, swz (p&15)<<4; all writes b128 via coalesced column-gather.
//  SCRATCH @32768 (32KB): Ph2 BwT[128n][256B] per t-half, swz (n&15)<<4;
//                          Ph3 P[64il][512B], swz (il&15)<<4.
//  scalars @65536: csL, dtL @+1024, wL @+2048, wsum @+3072.
__global__ __launch_bounds__(256) void ssd_kernel(const ushort_t* __restrict__ conv,
                                                  const float* __restrict__ dtA,
                                                  const float* __restrict__ Dvec,
                                                  const float* __restrict__ Avec,
                                                  ushort_t* __restrict__ yssm,
                                                  ushort_t* __restrict__ hst,
                                                  float* __restrict__ abprod) {
  const int bid = blockIdx.x;
  const int ck = bid & 7;
  const int h = (bid >> 3) & 63;
  const int b = bid >> 9;
  const int g = h >> 3;
  const int tid = threadIdx.x;
  const int lane = tid & 63;
  const int wv = tid >> 6;
  const int lr = lane & 15, lk = lane >> 4;
  const int btb = (b << 11) + (ck << 8);

  __shared__ __align__(16) unsigned char ldsb[68624];
  float* csL = (float*)(ldsb + 65536);
  float* dtL = (float*)(ldsb + 66560);
  float* wL  = (float*)(ldsb + 67584);
  float* wsum = (float*)(ldsb + 68608);

  const float Ah = Avec[h];
  const float Dh = Dvec[h];

  // ---- Ph0: inclusive cumsum of dt ----
  float dv = dtA[(h << 13) + btb + tid];
  float s = dv;
#pragma unroll
  for (int off = 1; off < 64; off <<= 1) {
    float t = __shfl_up(s, off, 64);
    if (lane >= off) s += t;
  }
  if (lane == 63) wsum[wv] = s;
  __syncthreads();
  float basev = 0.f;
  for (int i = 0; i < wv; ++i) basev += wsum[i];
  const float csv = basev + s;
  csL[tid] = csv;
  dtL[tid] = dv;
  __syncthreads();
  const float cstot = csL[255];
  wL[tid] = dv * expf(Ah * (cstot - csv));
  if (tid == 0) abprod[((b << 6) + h) * 8 + ck] = expf(Ah * cstot);

  // ---- Ph1: XT build via coalesced column gather + vectorized writes ----
  const ushort_t* Xg = conv + (size_t)btb * 6144 + (h << 6);
  {
    const int p = lane;
#pragma unroll
    for (int rep = 0; rep < 8; ++rep) {
      const int t0 = (rep * 4 + wv) << 3;
      u16x8 v;
#pragma unroll
      for (int k = 0; k < 8; ++k) v[k] = Xg[(size_t)(t0 + k) * 6144 + p];
      *(u16x8*)(ldsb + p * 512 + ((t0 * 2) ^ ((p & 15) << 4))) = v;
    }
  }
  __syncthreads();   // XT + wL visible

  // ---- Ph2: hst = XT * BwT^T, t in two halves of 128 (BwT in scratch) ----
  const ushort_t* Bg = conv + (size_t)btb * 6144 + 4096 + (g << 7);
  f32x4 hacc[4][2] = {};
  for (int th = 0; th < 2; ++th) {
#pragma unroll
    for (int rep = 0; rep < 8; ++rep) {
      const int n = ((rep & 1) << 6) | lane;
      const int tl0 = ((rep >> 1) * 4 + wv) << 3;        // within-half t
      const int t0 = th * 128 + tl0;
      u16x8 v;
#pragma unroll
      for (int k = 0; k < 8; ++k)
        v[k] = f2bf(bf2f(Bg[(size_t)(t0 + k) * 6144 + n]) * wL[t0 + k]);
      *(u16x8*)(ldsb + 32768 + n * 256 + ((tl0 * 2) ^ ((n & 15) << 4))) = v;
    }
    __syncthreads();
#pragma unroll
    for (int tc = 0; tc < 4; ++tc) {
      bf16x8 a4[4], b2[2];
#pragma unroll
      for (int pf = 0; pf < 4; ++pf) {
        const int p = pf * 16 + lr;
        a4[pf] = *(const bf16x8*)(ldsb + p * 512 +
                                  (((th * 128 + tc * 32 + lk * 8) * 2) ^ ((p & 15) << 4)));
      }
#pragma unroll
      for (int nf = 0; nf < 2; ++nf) {
        const int n = wv * 32 + nf * 16 + lr;
        b2[nf] = *(const bf16x8*)(ldsb + 32768 + n * 256 +
                                  (((tc * 32 + lk * 8) * 2) ^ ((n & 15) << 4)));
      }
#pragma unroll
      for (int pf = 0; pf < 4; ++pf)
#pragma unroll
        for (int nf = 0; nf < 2; ++nf)
          hacc[pf][nf] = __builtin_amdgcn_mfma_f32_16x16x32_bf16(a4[pf], b2[nf],
                                                                 hacc[pf][nf], 0, 0, 0);
    }
    __syncthreads();   // scratch free before next half / Ph3
  }
  // write hst (layout identical to prior rounds)
#pragma unroll
  for (int pf = 0; pf < 4; ++pf)
#pragma unroll
    for (int nf = 0; nf < 2; ++nf)
#pragma unroll
      for (int r = 0; r < 4; ++r) {
        int p = pf * 16 + (lk << 2) + r;
        int n = wv * 32 + nf * 16 + lr;
        hst[((size_t)((b << 10) | (h << 4) | ((p >> 5) << 3) | ck)) * 4096 +
            (size_t)(p & 31) * 128 + n] = f2bf(hacc[pf][nf][r]);
      }

  // ---- Ph3: per 64-row block: S -> mask -> P -> Y^T ----
  const ushort_t* Cg = conv + (size_t)btb * 6144 + 5120 + (g << 7);
  for (int rb = 0; rb < 4; ++rb) {
    const int i0 = rb << 6;
    f32x4 sacc[4][4] = {};
#pragma unroll
    for (int kk = 0; kk < 4; ++kk) {
      bf16x8 ca[4], bb[4];
#pragma unroll
      for (int ifr = 0; ifr < 4; ++ifr)
        ca[ifr] = *(const bf16x8*)(Cg + (size_t)(i0 + ifr * 16 + lr) * 6144 + kk * 32 + lk * 8);
#pragma unroll
      for (int jf = 0; jf < 4; ++jf)
        bb[jf] = *(const bf16x8*)(Bg + (size_t)(wv * 64 + jf * 16 + lr) * 6144 + kk * 32 + lk * 8);
#pragma unroll
      for (int ifr = 0; ifr < 4; ++ifr)
#pragma unroll
        for (int jf = 0; jf < 4; ++jf)
          sacc[ifr][jf] = __builtin_amdgcn_mfma_f32_16x16x32_bf16(ca[ifr], bb[jf],
                                                                  sacc[ifr][jf], 0, 0, 0);
    }
    // mask + write P (swz (il&15)<<4; il&15 = 4*lk + r spreads write slots)
#pragma unroll
    for (int ifr = 0; ifr < 4; ++ifr) {
#pragma unroll
      for (int jf = 0; jf < 4; ++jf) {
        int j = wv * 64 + jf * 16 + lr;
        float dtj = dtL[j], csj = csL[j];
#pragma unroll
        for (int r = 0; r < 4; ++r) {
          int il = ifr * 16 + (lk << 2) + r;
          int ig = i0 + il;
          float val = 0.f;
          if (j <= ig) val = sacc[ifr][jf][r] * dtj * expf(Ah * (csL[ig] - csj));
          *(ushort_t*)(ldsb + 32768 + il * 512 + ((j * 2) ^ ((il & 15) << 4))) = f2bf(val);
        }
      }
    }
    __syncthreads();
    // Y^T[p][i] = sum_j XT[p][j] * P[i][j]
    f32x4 yacc[4] = {};
    const int ilB = wv * 16 + lr;
#pragma unroll
    for (int ks = 0; ks < 8; ++ks) {
      bf16x8 pb = *(const bf16x8*)(ldsb + 32768 + ilB * 512 +
                                   (((ks * 32 + lk * 8) * 2) ^ ((ilB & 15) << 4)));
#pragma unroll
      for (int pf = 0; pf < 4; ++pf) {
        const int p = pf * 16 + lr;
        bf16x8 pa = *(const bf16x8*)(ldsb + p * 512 +
                                     (((ks * 32 + lk * 8) * 2) ^ ((p & 15) << 4)));
        yacc[pf] = __builtin_amdgcn_mfma_f32_16x16x32_bf16(pa, pb, yacc[pf], 0, 0, 0);
      }
    }
    // epilogue: + D*x, write yssm
    const int irow = i0 + wv * 16 + lr;
    const size_t ybase = (size_t)(btb + irow) * 4096 + (h << 6);
#pragma unroll
    for (int pf = 0; pf < 4; ++pf) {
      u16x4 o;
#pragma unroll
      for (int r = 0; r < 4; ++r) {
        int p = pf * 16 + (lk << 2) + r;
        float xv = bf2f(*(const ushort_t*)(ldsb + p * 512 +
                                           ((irow * 2) ^ ((p & 15) << 4))));
        o[r] = f2bf(yacc[pf][r] + Dh * xv);
      }
      *(u16x4*)(yssm + ybase + pf * 16 + (lk << 2)) = o;
    }
    __syncthreads();   // protect P before next rb overwrites it
  }
}

// ---------------- combine: prefix over chunk states (in place) ----------------
__global__ __launch_bounds__(256) void combine_kernel(ushort_t* __restrict__ hst,
                                                      const float* __restrict__ abprod) {
  const int bid = blockIdx.x;
  const int bh = bid >> 1;
  const int tid = threadIdx.x;
  const size_t base = (size_t)bid * 8 * 4096 + tid * 16;
  float hrun[16];
#pragma unroll
  for (int e = 0; e < 16; ++e) hrun[e] = 0.f;
  for (int c = 0; c < 8; ++c) {
    const size_t p = base + (size_t)c * 4096;
    u16x8 v0 = *(const u16x8*)&hst[p];
    u16x8 v1 = *(const u16x8*)&hst[p + 8];
    float ab = abprod[bh * 8 + c];
    u16x8 w0, w1;
#pragma unroll
    for (int e = 0; e < 8; ++e) { w0[e] = f2bf(hrun[e]); w1[e] = f2bf(hrun[8 + e]); }
    *(u16x8*)&hst[p] = w0;
    *(u16x8*)&hst[p + 8] = w1;
#pragma unroll
    for (int e = 0; e < 8; ++e) {
      hrun[e] = ab * hrun[e] + bf2f(v0[e]);
      hrun[8 + e] = ab * hrun[8 + e] + bf2f(v1[e]);
    }
  }
}

// ---------------- correction: yssm += pd[t] * (C_t . H_init) ------------------
__global__ __launch_bounds__(256) void correct_kernel(const ushort_t* __restrict__ conv,
                                                      const float* __restrict__ dtA,
                                                      const float* __restrict__ Avec,
                                                      const ushort_t* __restrict__ hst,
                                                      ushort_t* __restrict__ yssm) {
  const int bid = blockIdx.x;
  const int ck = bid & 7;
  const int h = (bid >> 3) & 63;
  const int b = bid >> 9;
  const int g = h >> 3;
  const int tid = threadIdx.x;
  const int lane = tid & 63;
  const int w = tid >> 6;
  const int lr = lane & 15, lk = lane >> 4;
  const int btb = (b << 11) + (ck << 8);

  __shared__ float pdl[256];
  __shared__ float wsum[4];
  float s = dtA[(h << 13) + btb + tid];
#pragma unroll
  for (int off = 1; off < 64; off <<= 1) {
    float t = __shfl_up(s, off, 64);
    if (lane >= off) s += t;
  }
  if (lane == 63) wsum[w] = s;
  __syncthreads();
  float basev = 0.f;
  for (int i = 0; i < w; ++i) basev += wsum[i];
  pdl[tid] = expf(Avec[h] * (basev + s));
  __syncthreads();

  const ushort_t* Cc = conv + (size_t)btb * 6144 + 5120 + (g << 7);
  const size_t hb0 = ((size_t)((b << 10) | (h << 4) | (0 << 3) | ck)) * 4096;
  const size_t hb1 = ((size_t)((b << 10) | (h << 4) | (1 << 3) | ck)) * 4096;

  f32x4 acc[4][4] = {};
#pragma unroll
  for (int kk = 0; kk < 4; ++kk) {
    const int k0 = kk * 32 + lk * 8;
    bf16x8 afr[4], bfr[4];
#pragma unroll
    for (int mf = 0; mf < 4; ++mf) {
      const int t = w * 64 + mf * 16 + lr;
      afr[mf] = *(const bf16x8*)(Cc + (size_t)t * 6144 + k0);
    }
#pragma unroll
    for (int nf = 0; nf < 4; ++nf) {
      const int p = nf * 16 + lr;
      const size_t hb = (p < 32) ? hb0 : hb1;
      bfr[nf] = *(const bf16x8*)(hst + hb + (size_t)(p & 31) * 128 + k0);
    }
#pragma unroll
    for (int mf = 0; mf < 4; ++mf)
#pragma unroll
      for (int nf = 0; nf < 4; ++nf)
        acc[mf][nf] = __builtin_amdgcn_mfma_f32_16x16x32_bf16(afr[mf], bfr[nf],
                                                              acc[mf][nf], 0, 0, 0);
  }

#pragma unroll
  for (int mf = 0; mf < 4; ++mf) {
#pragma unroll
    for (int r = 0; r < 4; ++r) {
      const int row = w * 64 + mf * 16 + (lk << 2) + r;
      const float pd = pdl[row];
      const size_t yrow = (size_t)(btb + row) * 4096 + (h << 6);
#pragma unroll
      for (int nf = 0; nf < 4; ++nf) {
        const int p = nf * 16 + lr;
        const size_t idx = yrow + p;
        yssm[idx] = f2bf(bf2f(yssm[idx]) + pd * acc[mf][nf][r]);
      }
    }
  }
}

// ---------------- gate * silu + RMSNorm -> bf16 -------------------------------
__global__ __launch_bounds__(256) void norm_kernel(const ushort_t* __restrict__ yssm,
                                                   const ushort_t* __restrict__ gate,
                                                   const float* __restrict__ nw,
                                                   ushort_t* __restrict__ out) {
  const int bt = blockIdx.x;
  const int tid = threadIdx.x;
  const ushort_t* y = yssm + (size_t)bt * 4096;
  const ushort_t* gt = gate + (size_t)bt * 4096;
  float vals[16];
  float ss = 0.f;
#pragma unroll
  for (int j = 0; j < 4; ++j) {
    int o = (tid + j * 256) << 2;
    u16x4 yv = *(const u16x4*)(y + o);
    u16x4 gv = *(const u16x4*)(gt + o);
#pragma unroll
    for (int e = 0; e < 4; ++e) {
      float v = bf2f(yv[e]) * siluf(bf2f(gv[e]));
      vals[j * 4 + e] = v;
      ss += v * v;
    }
  }
#pragma unroll
  for (int m = 1; m <= 32; m <<= 1) ss += __shfl_xor(ss, m, 64);
  __shared__ float red[4];
  if ((tid & 63) == 0) red[tid >> 6] = ss;
  __syncthreads();
  ss = red[0] + red[1] + red[2] + red[3];
  const float sc = rsqrtf(ss * (1.f / 4096.f) + 1e-5f);
#pragma unroll
  for (int j = 0; j < 4; ++j) {
    int o = (tid + j * 256) << 2;
    f32x4 wv = *(const f32x4*)(nw + o);
    u16x4 ov;
    ov.x = f2bf(vals[j * 4 + 0] * sc * wv.x);
    ov.y = f2bf(vals[j * 4 + 1] * sc * wv.y);
    ov.z = f2bf(vals[j * 4 + 2] * sc * wv.z);
    ov.w = f2bf(vals[j * 4 + 3] * sc * wv.w);
    *(u16x4*)(out + (size_t)bt * 4096 + o) = ov;
  }
}

// ------------------------------------------------------------------------------
extern "C" void kernel_launch(void* const* d_in, const int* in_sizes, int n_in,
                              void* d_out, int out_size, void* d_ws, size_t ws_size,
                              hipStream_t stream) {
  const float* hidden  = (const float*)d_in[0];
  const float* w_in    = (const float*)d_in[1];
  const float* conv_w  = (const float*)d_in[2];
  const float* conv_b  = (const float*)d_in[3];
  const float* Avec    = (const float*)d_in[4];
  const float* Dvec    = (const float*)d_in[5];
  const float* dt_bias = (const float*)d_in[6];
  const float* nw      = (const float*)d_in[7];
  const float* w_out   = (const float*)d_in[8];
  float* out = (float*)d_out;

  char* ws = (char*)d_ws;
  // Region map (total 162,693,120 B) — unchanged since R4.
  ushort_t* Xbf   = (ushort_t*)(ws);
  ushort_t* W1bf  = (ushort_t*)(ws + 22020096);
  ushort_t* gate  = (ushort_t*)(ws + 77758464);
  ushort_t* xbc   = (ushort_t*)(ws + 111312896);
  ushort_t* W2bf  = Xbf;
  ushort_t* convb = W1bf;
  float*    dtA   = (float*)(ws + 22020096 + 50331648);
  float*    abprod= (float*)(ws + 22020096 + 52428800);
  ushort_t* yssm  = xbc;
  ushort_t* hst   = (ushort_t*)(ws + 111312896 + 33554432);
  ushort_t* ynorm = convb;
  const size_t NEED = 162693120;
  if (NEED > ws_size) {
    fill_kernel<<<4, 256, 0, stream>>>(out, 12345.0f, 1024);   // sentinel: ws too small
    return;
  }

  cvt_bf16_kernel<<<10752, 256, 0, stream>>>(hidden, Xbf, 2752512, 2752512);
  cvt_bf16_kernel<<<27216, 256, 0, stream>>>(w_in, W1bf, 6924288, 6967296);
  gemm8_kernel<0><<<dim3(16, 41), 512, 0, stream>>>(Xbf, W1bf, gate, xbc,
                                                    2688, 10368, 10304, 21);
  cvt_bf16_kernel<<<10752, 256, 0, stream>>>(w_out, W2bf, 2752512, 2752512);
  conv_silu_kernel<<<24576, 256, 0, stream>>>(xbc, conv_w, conv_b, convb);
  dt_kernel<<<1024, 256, 0, stream>>>(xbc, dt_bias, Avec, dtA);
  ssd_kernel<<<1024, 256, 0, stream>>>(convb, dtA, Dvec, Avec, yssm, hst, abprod);
  combine_kernel<<<256, 256, 0, stream>>>(hst, abprod);
  correct_kernel<<<1024, 256, 0, stream>>>(convb, dtA, Avec, hst, yssm);
  norm_kernel<<<4096, 256, 0, stream>>>(yssm, gate, nw, ynorm);
  gemm8_kernel<1><<<dim3(16, 11), 512, 0, stream>>>(ynorm, W2bf, out, nullptr,
                                                    4096, 2688, 2688, 32);
}

// Round 13
// 663.729 us; speedup vs baseline: 1.1283x; 1.0724x over previous
//
#include <hip/hip_runtime.h>
#include <stdint.h>

typedef unsigned short ushort_t;
typedef __attribute__((ext_vector_type(4))) float f32x4;
typedef __attribute__((ext_vector_type(2))) float f32x2;
typedef __attribute__((ext_vector_type(8))) __bf16 bf16x8;
typedef __attribute__((ext_vector_type(4))) unsigned short u16x4;
typedef __attribute__((ext_vector_type(8))) unsigned short u16x8;

#define DEV __device__ __forceinline__

// async global->LDS, 16B per lane. HW: dest = wave-uniform base + laneID*16.
DEV void gload_lds16(const void* g, void* l) {
  __builtin_amdgcn_global_load_lds(
      (const __attribute__((address_space(1))) uint32_t*)(uintptr_t)(g),
      (__attribute__((address_space(3))) uint32_t*)(uintptr_t)(l), 16, 0, 0);
}

DEV ushort_t f2bf(float f) {
  union { float f; uint32_t u; } x; x.f = f;
  x.u += 0x7fffu + ((x.u >> 16) & 1u);   // RNE
  return (ushort_t)(x.u >> 16);
}

DEV float bf2f(ushort_t u) {
  union { uint32_t u; float f; } x; x.u = (uint32_t)u << 16; return x.f;
}

DEV float siluf(float x) { return x / (1.f + expf(-x)); }

// single-instruction exp2 (v_exp_f32); fallback keeps it compiling anywhere
DEV float fexp2(float x) {
#if __has_builtin(__builtin_amdgcn_exp2f)
  return __builtin_amdgcn_exp2f(x);
#else
  return exp2f(x);
#endif
}

#define BAR asm volatile("s_barrier" ::: "memory")
#define LGKM0 do { asm volatile("s_waitcnt lgkmcnt(0)" ::: "memory"); \
                   __builtin_amdgcn_sched_barrier(0); } while (0)
#define VMCNT(n) asm volatile("s_waitcnt vmcnt(" #n ")" ::: "memory")

// ---------------- sentinel fill (diagnostic) ----------------------------------
__global__ __launch_bounds__(256) void fill_kernel(float* p, float v, int n) {
  int i = blockIdx.x * 256 + threadIdx.x;
  if (i < n) p[i] = v;
}

// ---------------- f32 -> bf16 convert (with zero tail padding) ---------------
__global__ __launch_bounds__(256) void cvt_bf16_kernel(const float* __restrict__ src,
                                                       ushort_t* __restrict__ dst,
                                                       int n_src4, int n_dst4) {
  int i = blockIdx.x * 256 + threadIdx.x;
  if (i >= n_dst4) return;
  f32x4 v;
  if (i < n_src4) v = *(const f32x4*)(src + (size_t)i * 4);
  else { v.x = 0.f; v.y = 0.f; v.z = 0.f; v.w = 0.f; }
  u16x4 o;
  o.x = f2bf(v.x); o.y = f2bf(v.y); o.z = f2bf(v.z); o.w = f2bf(v.w);
  *(u16x4*)(dst + (size_t)i * 4) = o;
}

// ================= 256x256 8-phase bf16 GEMM (T2+T3+T4+T5) ====================
// (R12 version, unchanged: natural dispatch order; no redundant ld_b2 at P4/P8)
DEV void ld_a4(const unsigned char* ab2, int mgofs, int ck0, int ck1, bf16x8 (&af)[4][2]) {
#pragma unroll
  for (int mi = 0; mi < 4; ++mi) {
    const unsigned char* p = ab2 + (mgofs + mi * 16) * 128;
    af[mi][0] = *(const bf16x8*)(p + ck0);
    af[mi][1] = *(const bf16x8*)(p + ck1);
  }
}

DEV void ld_b2(const unsigned char* bb2, int npofs, int ck0, int ck1, bf16x8 (&bf)[2][2]) {
#pragma unroll
  for (int ni = 0; ni < 2; ++ni) {
    const unsigned char* p = bb2 + (npofs + ni * 16) * 128;
    bf[ni][0] = *(const bf16x8*)(p + ck0);
    bf[ni][1] = *(const bf16x8*)(p + ck1);
  }
}

DEV void mm16(f32x4 (&acc)[8][4], const bf16x8 (&af)[4][2], const bf16x8 (&bf)[2][2],
              int mb, int nb) {
  __builtin_amdgcn_s_setprio(1);
#pragma unroll
  for (int mi = 0; mi < 4; ++mi)
#pragma unroll
    for (int ni = 0; ni < 2; ++ni)
#pragma unroll
      for (int kk = 0; kk < 2; ++kk)
        acc[mb + mi][nb + ni] = __builtin_amdgcn_mfma_f32_16x16x32_bf16(
            af[mi][kk], bf[ni][kk], acc[mb + mi][nb + ni], 0, 0, 0);
  __builtin_amdgcn_s_setprio(0);
}

DEV void stage2(const ushort_t* s0, const ushort_t* s1, unsigned char* d) {
  gload_lds16(s0, d);
  gload_lds16(s1, d + 8192);
}

template <int MODE>
__global__ __launch_bounds__(512, 1) void gemm8_kernel(const ushort_t* __restrict__ A,
                                                       const ushort_t* __restrict__ B,
                                                       void* __restrict__ C0,
                                                       void* __restrict__ C1,
                                                       int K, int NB, int NC, int niter) {
  __shared__ __align__(16) unsigned char lds[131072];
  const int tid = threadIdx.x;
  const int l = tid & 63, w = tid >> 6;
  const int wr = w >> 2, wc = w & 3;
  const int lr = l & 15, lk = l >> 4;
  const int xm = (lr & 7) << 4;
  const int ck0 = (lk * 16) ^ xm;
  const int ck1 = (64 + lk * 16) ^ xm;
  const int bm = blockIdx.x, bn = blockIdx.y;

  const int rr = (w << 3) + (l >> 3);
  const int cE = ((l & 7) ^ (l >> 3)) << 3;
  const int dstoff = w * 1024 + l * 16;

  const ushort_t* sA00 = A + (size_t)(bm * 256 +       rr) * K + cE;
  const ushort_t* sA01 = A + (size_t)(bm * 256 +  64 + rr) * K + cE;
  const ushort_t* sA10 = A + (size_t)(bm * 256 + 128 + rr) * K + cE;
  const ushort_t* sA11 = A + (size_t)(bm * 256 + 192 + rr) * K + cE;
  int rb0 = bn * 256 +       rr; if (rb0 > NB - 1) rb0 = NB - 1;
  int rb1 = bn * 256 +  64 + rr; if (rb1 > NB - 1) rb1 = NB - 1;
  int rb2 = bn * 256 + 128 + rr; if (rb2 > NB - 1) rb2 = NB - 1;
  int rb3 = bn * 256 + 192 + rr; if (rb3 > NB - 1) rb3 = NB - 1;
  const ushort_t* sB00 = B + (size_t)rb0 * K + cE;
  const ushort_t* sB01 = B + (size_t)rb1 * K + cE;
  const ushort_t* sB10 = B + (size_t)rb2 * K + cE;
  const ushort_t* sB11 = B + (size_t)rb3 * K + cE;

  const int aoff = wr * 16384 + lr * 128;
  const int boff = 32768 + (wc >> 1) * 16384 + ((wc & 1) * 64 + lr) * 128;

  f32x4 acc[8][4] = {};
  bf16x8 af[4][2], bf[2][2], bg[2][2];

  stage2(sA00, sA01, lds + dstoff);
  stage2(sA10, sA11, lds + 16384 + dstoff);
  stage2(sB00, sB01, lds + 32768 + dstoff);
  stage2(sB10, sB11, lds + 49152 + dstoff);
  stage2(sA00 + 64, sA01 + 64, lds + 65536 + dstoff);
  VMCNT(2);
  BAR;

  auto kpair = [&](int kt0, bool last) {
    const unsigned char* a0 = lds + aoff;
    const unsigned char* b0 = lds + boff;
    const unsigned char* a1 = lds + 65536 + aoff;
    const unsigned char* b1 = lds + 65536 + boff;
    const size_t c1 = (size_t)(kt0 + 1) * 64;
    const size_t c2 = (size_t)(kt0 + 2) * 64;
    const size_t c3 = (size_t)(kt0 + 3) * 64;
    ld_a4(a0, 0, ck0, ck1, af);
    ld_b2(b0, 0, ck0, ck1, bf);
    stage2(sA10 + c1, sA11 + c1, lds + 65536 + 16384 + dstoff);
    BAR; LGKM0; mm16(acc, af, bf, 0, 0); BAR;
    ld_b2(b0, 32, ck0, ck1, bg);
    stage2(sB00 + c1, sB01 + c1, lds + 65536 + 32768 + dstoff);
    BAR; LGKM0; mm16(acc, af, bg, 0, 2); BAR;
    ld_a4(a0, 64, ck0, ck1, af);
    stage2(sB10 + c1, sB11 + c1, lds + 65536 + 49152 + dstoff);
    BAR; LGKM0; mm16(acc, af, bg, 4, 2); BAR;
    if (!last) { stage2(sA00 + c2, sA01 + c2, lds + dstoff); VMCNT(2); }
    else       { VMCNT(0); }
    BAR; LGKM0; mm16(acc, af, bf, 4, 0); BAR;
    ld_a4(a1, 0, ck0, ck1, af);
    ld_b2(b1, 0, ck0, ck1, bf);
    if (!last) stage2(sA10 + c2, sA11 + c2, lds + 16384 + dstoff);
    BAR; LGKM0; mm16(acc, af, bf, 0, 0); BAR;
    ld_b2(b1, 32, ck0, ck1, bg);
    if (!last) stage2(sB00 + c2, sB01 + c2, lds + 32768 + dstoff);
    BAR; LGKM0; mm16(acc, af, bg, 0, 2); BAR;
    ld_a4(a1, 64, ck0, ck1, af);
    if (!last) stage2(sB10 + c2, sB11 + c2, lds + 49152 + dstoff);
    BAR; LGKM0; mm16(acc, af, bg, 4, 2); BAR;
    if (!last) { stage2(sA00 + c3, sA01 + c3, lds + 65536 + dstoff); VMCNT(2); }
    BAR; LGKM0; mm16(acc, af, bf, 4, 0); BAR;
  };

  for (int it = 0; it < niter - 1; ++it) kpair(2 * it, false);
  kpair(2 * (niter - 1), true);

  const int crow0 = bm * 256 + wr * 128 + (lk << 2);
  const int ccol0 = bn * 256 + wc * 64 + lr;
  if (MODE == 0) {
    ushort_t* gate = (ushort_t*)C0;
    ushort_t* xbc  = (ushort_t*)C1;
#pragma unroll
    for (int ni = 0; ni < 4; ++ni) {
      const int col = ccol0 + ni * 16;
      if (col < NC) {
        ushort_t* dst; size_t stride;
        if (col < 4096) { dst = gate + col; stride = 4096; }
        else            { dst = xbc + (col - 4096); stride = 6272; }
#pragma unroll
        for (int mi = 0; mi < 8; ++mi)
#pragma unroll
          for (int r = 0; r < 4; ++r)
            dst[(size_t)(crow0 + mi * 16 + r) * stride] = f2bf(acc[mi][ni][r]);
      }
    }
  } else {
    float* o = (float*)C0;
#pragma unroll
    for (int ni = 0; ni < 4; ++ni) {
      const int col = ccol0 + ni * 16;
      if (col < NC) {
#pragma unroll
        for (int mi = 0; mi < 8; ++mi)
#pragma unroll
          for (int r = 0; r < 4; ++r)
            o[(size_t)(crow0 + mi * 16 + r) * NC + col] = acc[mi][ni][r];
      }
    }
  }
}

// ---------------- causal depthwise conv (K=4) + bias + SiLU, bf16 in/out ------
__global__ __launch_bounds__(256) void conv_silu_kernel(const ushort_t* __restrict__ xbc,
                                                        const float* __restrict__ cw,
                                                        const float* __restrict__ cb,
                                                        ushort_t* __restrict__ out) {
  int idx = blockIdx.x * 256 + threadIdx.x;      // 4096*1536
  int c4 = (idx % 1536) << 2;
  int bt = idx / 1536;
  int t = bt & 2047;
  const ushort_t* base = xbc + (size_t)bt * 6272 + c4;
  f32x4 w0 = *(const f32x4*)&cw[(c4 + 0) * 4];
  f32x4 w1 = *(const f32x4*)&cw[(c4 + 1) * 4];
  f32x4 w2 = *(const f32x4*)&cw[(c4 + 2) * 4];
  f32x4 w3 = *(const f32x4*)&cw[(c4 + 3) * 4];
  f32x4 acc = *(const f32x4*)&cb[c4];
#pragma unroll
  for (int i = 0; i < 4; ++i) {
    int dt_ = i - 3;
    if (t + dt_ >= 0) {
      u16x4 xv = *(const u16x4*)(base + (ptrdiff_t)dt_ * 6272);
      acc.x += bf2f(xv.x) * w0[i];
      acc.y += bf2f(xv.y) * w1[i];
      acc.z += bf2f(xv.z) * w2[i];
      acc.w += bf2f(xv.w) * w3[i];
    }
  }
  u16x4 o;
  o.x = f2bf(siluf(acc.x)); o.y = f2bf(siluf(acc.y));
  o.z = f2bf(siluf(acc.z)); o.w = f2bf(siluf(acc.w));
  *(u16x4*)(out + (size_t)bt * 6144 + c4) = o;
}

// ---------------- dt: softplus + exp(A*dt), layout [H][2][BT] f32 -------------
__global__ __launch_bounds__(256) void dt_kernel(const ushort_t* __restrict__ xbc,
                                                 const float* __restrict__ dt_bias,
                                                 const float* __restrict__ Avec,
                                                 float* __restrict__ dtA) {
  int idx = blockIdx.x * 256 + threadIdx.x;      // 64*4096
  int h = idx >> 12, bt = idx & 4095;
  float v = bf2f(xbc[(size_t)bt * 6272 + 6144 + h]) + dt_bias[h];
  float sp = fmaxf(v, 0.f) + log1pf(expf(-fabsf(v)));
  float ab = expf(Avec[h] * sp);
  dtA[(h << 13) + bt] = sp;
  dtA[(h << 13) + 4096 + bt] = ab;
}

// ---------------- SSD chunk kernel (R13: exp2-factored decay mask) ------------
// R12 layouts kept (all writes vectorized/conflict-free). R13 change: the P
// mask used 256 expf/thread (~3000 VALU) — now a precomputed l2[t] =
// A*cs_t*log2e lets each element use ONE v_exp_f32: exp2(l2[i]-l2[j])
// (arg<=0 for j<=i: underflow-safe). Fully-masked fragments (wave-uniform
// test) skip exp/mul entirely and write zeros.
__global__ __launch_bounds__(256) void ssd_kernel(const ushort_t* __restrict__ conv,
                                                  const float* __restrict__ dtA,
                                                  const float* __restrict__ Dvec,
                                                  const float* __restrict__ Avec,
                                                  ushort_t* __restrict__ yssm,
                                                  ushort_t* __restrict__ hst,
                                                  float* __restrict__ abprod) {
  const int bid = blockIdx.x;
  const int ck = bid & 7;
  const int h = (bid >> 3) & 63;
  const int b = bid >> 9;
  const int g = h >> 3;
  const int tid = threadIdx.x;
  const int lane = tid & 63;
  const int wv = tid >> 6;
  const int lr = lane & 15, lk = lane >> 4;
  const int btb = (b << 11) + (ck << 8);

  // 0..32767: XT[64p][512B] swz (p&15)<<4 | 32768..65535: scratch (BwT / P)
  // 65536: csL[256] | 66560: dtL | 67584: wL | 68608: l2L | 69632: wsum
  __shared__ __align__(16) unsigned char ldsb[69648];
  float* csL = (float*)(ldsb + 65536);
  float* dtL = (float*)(ldsb + 66560);
  float* wL  = (float*)(ldsb + 67584);
  float* l2L = (float*)(ldsb + 68608);
  float* wsum = (float*)(ldsb + 69632);

  const float Ah = Avec[h];
  const float Dh = Dvec[h];
  const float AhL2 = Ah * 1.44269504f;

  // ---- Ph0: inclusive cumsum of dt ----
  float dv = dtA[(h << 13) + btb + tid];
  float s = dv;
#pragma unroll
  for (int off = 1; off < 64; off <<= 1) {
    float t = __shfl_up(s, off, 64);
    if (lane >= off) s += t;
  }
  if (lane == 63) wsum[wv] = s;
  __syncthreads();
  float basev = 0.f;
  for (int i = 0; i < wv; ++i) basev += wsum[i];
  const float csv = basev + s;
  csL[tid] = csv;
  dtL[tid] = dv;
  l2L[tid] = AhL2 * csv;
  __syncthreads();
  const float cstot = csL[255];
  wL[tid] = dv * fexp2(AhL2 * (cstot - csv));
  if (tid == 0) abprod[((b << 6) + h) * 8 + ck] = expf(Ah * cstot);

  // ---- Ph1: XT build via coalesced column gather + vectorized writes ----
  const ushort_t* Xg = conv + (size_t)btb * 6144 + (h << 6);
  {
    const int p = lane;
#pragma unroll
    for (int rep = 0; rep < 8; ++rep) {
      const int t0 = (rep * 4 + wv) << 3;
      u16x8 v;
#pragma unroll
      for (int k = 0; k < 8; ++k) v[k] = Xg[(size_t)(t0 + k) * 6144 + p];
      *(u16x8*)(ldsb + p * 512 + ((t0 * 2) ^ ((p & 15) << 4))) = v;
    }
  }
  __syncthreads();   // XT + wL visible

  // ---- Ph2: hst = XT * BwT^T, t in two halves of 128 (BwT in scratch) ----
  const ushort_t* Bg = conv + (size_t)btb * 6144 + 4096 + (g << 7);
  f32x4 hacc[4][2] = {};
  for (int th = 0; th < 2; ++th) {
#pragma unroll
    for (int rep = 0; rep < 8; ++rep) {
      const int n = ((rep & 1) << 6) | lane;
      const int tl0 = ((rep >> 1) * 4 + wv) << 3;        // within-half t
      const int t0 = th * 128 + tl0;
      u16x8 v;
#pragma unroll
      for (int k = 0; k < 8; ++k)
        v[k] = f2bf(bf2f(Bg[(size_t)(t0 + k) * 6144 + n]) * wL[t0 + k]);
      *(u16x8*)(ldsb + 32768 + n * 256 + ((tl0 * 2) ^ ((n & 15) << 4))) = v;
    }
    __syncthreads();
#pragma unroll
    for (int tc = 0; tc < 4; ++tc) {
      bf16x8 a4[4], b2[2];
#pragma unroll
      for (int pf = 0; pf < 4; ++pf) {
        const int p = pf * 16 + lr;
        a4[pf] = *(const bf16x8*)(ldsb + p * 512 +
                                  (((th * 128 + tc * 32 + lk * 8) * 2) ^ ((p & 15) << 4)));
      }
#pragma unroll
      for (int nf = 0; nf < 2; ++nf) {
        const int n = wv * 32 + nf * 16 + lr;
        b2[nf] = *(const bf16x8*)(ldsb + 32768 + n * 256 +
                                  (((tc * 32 + lk * 8) * 2) ^ ((n & 15) << 4)));
      }
#pragma unroll
      for (int pf = 0; pf < 4; ++pf)
#pragma unroll
        for (int nf = 0; nf < 2; ++nf)
          hacc[pf][nf] = __builtin_amdgcn_mfma_f32_16x16x32_bf16(a4[pf], b2[nf],
                                                                 hacc[pf][nf], 0, 0, 0);
    }
    __syncthreads();   // scratch free before next half / Ph3
  }
  // write hst (layout identical to prior rounds)
#pragma unroll
  for (int pf = 0; pf < 4; ++pf)
#pragma unroll
    for (int nf = 0; nf < 2; ++nf)
#pragma unroll
      for (int r = 0; r < 4; ++r) {
        int p = pf * 16 + (lk << 2) + r;
        int n = wv * 32 + nf * 16 + lr;
        hst[((size_t)((b << 10) | (h << 4) | ((p >> 5) << 3) | ck)) * 4096 +
            (size_t)(p & 31) * 128 + n] = f2bf(hacc[pf][nf][r]);
      }

  // ---- Ph3: per 64-row block: S -> mask -> P -> Y^T ----
  const ushort_t* Cg = conv + (size_t)btb * 6144 + 5120 + (g << 7);
  for (int rb = 0; rb < 4; ++rb) {
    const int i0 = rb << 6;
    f32x4 sacc[4][4] = {};
#pragma unroll
    for (int kk = 0; kk < 4; ++kk) {
      bf16x8 ca[4], bb[4];
#pragma unroll
      for (int ifr = 0; ifr < 4; ++ifr)
        ca[ifr] = *(const bf16x8*)(Cg + (size_t)(i0 + ifr * 16 + lr) * 6144 + kk * 32 + lk * 8);
#pragma unroll
      for (int jf = 0; jf < 4; ++jf)
        bb[jf] = *(const bf16x8*)(Bg + (size_t)(wv * 64 + jf * 16 + lr) * 6144 + kk * 32 + lk * 8);
#pragma unroll
      for (int ifr = 0; ifr < 4; ++ifr)
#pragma unroll
        for (int jf = 0; jf < 4; ++jf)
          sacc[ifr][jf] = __builtin_amdgcn_mfma_f32_16x16x32_bf16(ca[ifr], bb[jf],
                                                                  sacc[ifr][jf], 0, 0, 0);
    }
    // mask + write P (swz (il&15)<<4). Decay via single-instr exp2.
#pragma unroll
    for (int ifr = 0; ifr < 4; ++ifr) {
      const int ibmax = i0 + ifr * 16 + 15;
#pragma unroll
      for (int jf = 0; jf < 4; ++jf) {
        const int jbmin = wv * 64 + jf * 16;          // wave-uniform
        const int j = jbmin + lr;
        if (jbmin > ibmax) {
          // fragment entirely above diagonal: zeros, no exp/mul
#pragma unroll
          for (int r = 0; r < 4; ++r) {
            int il = ifr * 16 + (lk << 2) + r;
            *(ushort_t*)(ldsb + 32768 + il * 512 + ((j * 2) ^ ((il & 15) << 4))) = 0;
          }
        } else {
          const float dtj = dtL[j];
          const float l2j = l2L[j];
#pragma unroll
          for (int r = 0; r < 4; ++r) {
            int il = ifr * 16 + (lk << 2) + r;
            int ig = i0 + il;
            float val = 0.f;
            if (j <= ig) val = sacc[ifr][jf][r] * dtj * fexp2(l2L[ig] - l2j);
            *(ushort_t*)(ldsb + 32768 + il * 512 + ((j * 2) ^ ((il & 15) << 4))) = f2bf(val);
          }
        }
      }
    }
    __syncthreads();
    // Y^T[p][i] = sum_j XT[p][j] * P[i][j]
    f32x4 yacc[4] = {};
    const int ilB = wv * 16 + lr;
#pragma unroll
    for (int ks = 0; ks < 8; ++ks) {
      bf16x8 pb = *(const bf16x8*)(ldsb + 32768 + ilB * 512 +
                                   (((ks * 32 + lk * 8) * 2) ^ ((ilB & 15) << 4)));
#pragma unroll
      for (int pf = 0; pf < 4; ++pf) {
        const int p = pf * 16 + lr;
        bf16x8 pa = *(const bf16x8*)(ldsb + p * 512 +
                                     (((ks * 32 + lk * 8) * 2) ^ ((p & 15) << 4)));
        yacc[pf] = __builtin_amdgcn_mfma_f32_16x16x32_bf16(pa, pb, yacc[pf], 0, 0, 0);
      }
    }
    // epilogue: + D*x, write yssm
    const int irow = i0 + wv * 16 + lr;
    const size_t ybase = (size_t)(btb + irow) * 4096 + (h << 6);
#pragma unroll
    for (int pf = 0; pf < 4; ++pf) {
      u16x4 o;
#pragma unroll
      for (int r = 0; r < 4; ++r) {
        int p = pf * 16 + (lk << 2) + r;
        float xv = bf2f(*(const ushort_t*)(ldsb + p * 512 +
                                           ((irow * 2) ^ ((p & 15) << 4))));
        o[r] = f2bf(yacc[pf][r] + Dh * xv);
      }
      *(u16x4*)(yssm + ybase + pf * 16 + (lk << 2)) = o;
    }
    __syncthreads();   // protect P before next rb overwrites it
  }
}

// ---------------- combine: prefix over chunk states (in place) ----------------
__global__ __launch_bounds__(256) void combine_kernel(ushort_t* __restrict__ hst,
                                                      const float* __restrict__ abprod) {
  const int bid = blockIdx.x;
  const int bh = bid >> 1;
  const int tid = threadIdx.x;
  const size_t base = (size_t)bid * 8 * 4096 + tid * 16;
  float hrun[16];
#pragma unroll
  for (int e = 0; e < 16; ++e) hrun[e] = 0.f;
  for (int c = 0; c < 8; ++c) {
    const size_t p = base + (size_t)c * 4096;
    u16x8 v0 = *(const u16x8*)&hst[p];
    u16x8 v1 = *(const u16x8*)&hst[p + 8];
    float ab = abprod[bh * 8 + c];
    u16x8 w0, w1;
#pragma unroll
    for (int e = 0; e < 8; ++e) { w0[e] = f2bf(hrun[e]); w1[e] = f2bf(hrun[8 + e]); }
    *(u16x8*)&hst[p] = w0;
    *(u16x8*)&hst[p + 8] = w1;
#pragma unroll
    for (int e = 0; e < 8; ++e) {
      hrun[e] = ab * hrun[e] + bf2f(v0[e]);
      hrun[8 + e] = ab * hrun[8 + e] + bf2f(v1[e]);
    }
  }
}

// ---------------- correction: yssm += pd[t] * (C_t . H_init) ------------------
__global__ __launch_bounds__(256) void correct_kernel(const ushort_t* __restrict__ conv,
                                                      const float* __restrict__ dtA,
                                                      const float* __restrict__ Avec,
                                                      const ushort_t* __restrict__ hst,
                                                      ushort_t* __restrict__ yssm) {
  const int bid = blockIdx.x;
  const int ck = bid & 7;
  const int h = (bid >> 3) & 63;
  const int b = bid >> 9;
  const int g = h >> 3;
  const int tid = threadIdx.x;
  const int lane = tid & 63;
  const int w = tid >> 6;
  const int lr = lane & 15, lk = lane >> 4;
  const int btb = (b << 11) + (ck << 8);

  __shared__ float pdl[256];
  __shared__ float wsum[4];
  float s = dtA[(h << 13) + btb + tid];
#pragma unroll
  for (int off = 1; off < 64; off <<= 1) {
    float t = __shfl_up(s, off, 64);
    if (lane >= off) s += t;
  }
  if (lane == 63) wsum[w] = s;
  __syncthreads();
  float basev = 0.f;
  for (int i = 0; i < w; ++i) basev += wsum[i];
  pdl[tid] = expf(Avec[h] * (basev + s));
  __syncthreads();

  const ushort_t* Cc = conv + (size_t)btb * 6144 + 5120 + (g << 7);
  const size_t hb0 = ((size_t)((b << 10) | (h << 4) | (0 << 3) | ck)) * 4096;
  const size_t hb1 = ((size_t)((b << 10) | (h << 4) | (1 << 3) | ck)) * 4096;

  f32x4 acc[4][4] = {};
#pragma unroll
  for (int kk = 0; kk < 4; ++kk) {
    const int k0 = kk * 32 + lk * 8;
    bf16x8 afr[4], bfr[4];
#pragma unroll
    for (int mf = 0; mf < 4; ++mf) {
      const int t = w * 64 + mf * 16 + lr;
      afr[mf] = *(const bf16x8*)(Cc + (size_t)t * 6144 + k0);
    }
#pragma unroll
    for (int nf = 0; nf < 4; ++nf) {
      const int p = nf * 16 + lr;
      const size_t hb = (p < 32) ? hb0 : hb1;
      bfr[nf] = *(const bf16x8*)(hst + hb + (size_t)(p & 31) * 128 + k0);
    }
#pragma unroll
    for (int mf = 0; mf < 4; ++mf)
#pragma unroll
      for (int nf = 0; nf < 4; ++nf)
        acc[mf][nf] = __builtin_amdgcn_mfma_f32_16x16x32_bf16(afr[mf], bfr[nf],
                                                              acc[mf][nf], 0, 0, 0);
  }

#pragma unroll
  for (int mf = 0; mf < 4; ++mf) {
#pragma unroll
    for (int r = 0; r < 4; ++r) {
      const int row = w * 64 + mf * 16 + (lk << 2) + r;
      const float pd = pdl[row];
      const size_t yrow = (size_t)(btb + row) * 4096 + (h << 6);
#pragma unroll
      for (int nf = 0; nf < 4; ++nf) {
        const int p = nf * 16 + lr;
        const size_t idx = yrow + p;
        yssm[idx] = f2bf(bf2f(yssm[idx]) + pd * acc[mf][nf][r]);
      }
    }
  }
}

// ---------------- gate * silu + RMSNorm -> bf16 -------------------------------
__global__ __launch_bounds__(256) void norm_kernel(const ushort_t* __restrict__ yssm,
                                                   const ushort_t* __restrict__ gate,
                                                   const float* __restrict__ nw,
                                                   ushort_t* __restrict__ out) {
  const int bt = blockIdx.x;
  const int tid = threadIdx.x;
  const ushort_t* y = yssm + (size_t)bt * 4096;
  const ushort_t* gt = gate + (size_t)bt * 4096;
  float vals[16];
  float ss = 0.f;
#pragma unroll
  for (int j = 0; j < 4; ++j) {
    int o = (tid + j * 256) << 2;
    u16x4 yv = *(const u16x4*)(y + o);
    u16x4 gv = *(const u16x4*)(gt + o);
#pragma unroll
    for (int e = 0; e < 4; ++e) {
      float v = bf2f(yv[e]) * siluf(bf2f(gv[e]));
      vals[j * 4 + e] = v;
      ss += v * v;
    }
  }
#pragma unroll
  for (int m = 1; m <= 32; m <<= 1) ss += __shfl_xor(ss, m, 64);
  __shared__ float red[4];
  if ((tid & 63) == 0) red[tid >> 6] = ss;
  __syncthreads();
  ss = red[0] + red[1] + red[2] + red[3];
  const float sc = rsqrtf(ss * (1.f / 4096.f) + 1e-5f);
#pragma unroll
  for (int j = 0; j < 4; ++j) {
    int o = (tid + j * 256) << 2;
    f32x4 wv = *(const f32x4*)(nw + o);
    u16x4 ov;
    ov.x = f2bf(vals[j * 4 + 0] * sc * wv.x);
    ov.y = f2bf(vals[j * 4 + 1] * sc * wv.y);
    ov.z = f2bf(vals[j * 4 + 2] * sc * wv.z);
    ov.w = f2bf(vals[j * 4 + 3] * sc * wv.w);
    *(u16x4*)(out + (size_t)bt * 4096 + o) = ov;
  }
}

// ------------------------------------------------------------------------------
extern "C" void kernel_launch(void* const* d_in, const int* in_sizes, int n_in,
                              void* d_out, int out_size, void* d_ws, size_t ws_size,
                              hipStream_t stream) {
  const float* hidden  = (const float*)d_in[0];
  const float* w_in    = (const float*)d_in[1];
  const float* conv_w  = (const float*)d_in[2];
  const float* conv_b  = (const float*)d_in[3];
  const float* Avec    = (const float*)d_in[4];
  const float* Dvec    = (const float*)d_in[5];
  const float* dt_bias = (const float*)d_in[6];
  const float* nw      = (const float*)d_in[7];
  const float* w_out   = (const float*)d_in[8];
  float* out = (float*)d_out;

  char* ws = (char*)d_ws;
  // Region map (total 162,693,120 B) — unchanged since R4.
  ushort_t* Xbf   = (ushort_t*)(ws);
  ushort_t* W1bf  = (ushort_t*)(ws + 22020096);
  ushort_t* gate  = (ushort_t*)(ws + 77758464);
  ushort_t* xbc   = (ushort_t*)(ws + 111312896);
  ushort_t* W2bf  = Xbf;
  ushort_t* convb = W1bf;
  float*    dtA   = (float*)(ws + 22020096 + 50331648);
  float*    abprod= (float*)(ws + 22020096 + 52428800);
  ushort_t* yssm  = xbc;
  ushort_t* hst   = (ushort_t*)(ws + 111312896 + 33554432);
  ushort_t* ynorm = convb;
  const size_t NEED = 162693120;
  if (NEED > ws_size) {
    fill_kernel<<<4, 256, 0, stream>>>(out, 12345.0f, 1024);   // sentinel: ws too small
    return;
  }

  cvt_bf16_kernel<<<10752, 256, 0, stream>>>(hidden, Xbf, 2752512, 2752512);
  cvt_bf16_kernel<<<27216, 256, 0, stream>>>(w_in, W1bf, 6924288, 6967296);
  gemm8_kernel<0><<<dim3(16, 41), 512, 0, stream>>>(Xbf, W1bf, gate, xbc,
                                                    2688, 10368, 10304, 21);
  cvt_bf16_kernel<<<10752, 256, 0, stream>>>(w_out, W2bf, 2752512, 2752512);
  conv_silu_kernel<<<24576, 256, 0, stream>>>(xbc, conv_w, conv_b, convb);
  dt_kernel<<<1024, 256, 0, stream>>>(xbc, dt_bias, Avec, dtA);
  ssd_kernel<<<1024, 256, 0, stream>>>(convb, dtA, Dvec, Avec, yssm, hst, abprod);
  combine_kernel<<<256, 256, 0, stream>>>(hst, abprod);
  correct_kernel<<<1024, 256, 0, stream>>>(convb, dtA, Avec, hst, yssm);
  norm_kernel<<<4096, 256, 0, stream>>>(yssm, gate, nw, ynorm);
  gemm8_kernel<1><<<dim3(16, 11), 512, 0, stream>>>(ynorm, W2bf, out, nullptr,
                                                    4096, 2688, 2688, 32);
}

// Round 14
// 658.228 us; speedup vs baseline: 1.1378x; 1.0084x over previous
//
#include <hip/hip_runtime.h>
#include <stdint.h>

typedef unsigned short ushort_t;
typedef __attribute__((ext_vector_type(4))) float f32x4;
typedef __attribute__((ext_vector_type(2))) float f32x2;
typedef __attribute__((ext_vector_type(8))) __bf16 bf16x8;
typedef __attribute__((ext_vector_type(4))) unsigned short u16x4;
typedef __attribute__((ext_vector_type(8))) unsigned short u16x8;

#define DEV __device__ __forceinline__

// async global->LDS, 16B per lane. HW: dest = wave-uniform base + laneID*16.
DEV void gload_lds16(const void* g, void* l) {
  __builtin_amdgcn_global_load_lds(
      (const __attribute__((address_space(1))) uint32_t*)(uintptr_t)(g),
      (__attribute__((address_space(3))) uint32_t*)(uintptr_t)(l), 16, 0, 0);
}

DEV ushort_t f2bf(float f) {
  union { float f; uint32_t u; } x; x.f = f;
  x.u += 0x7fffu + ((x.u >> 16) & 1u);   // RNE
  return (ushort_t)(x.u >> 16);
}

DEV float bf2f(ushort_t u) {
  union { uint32_t u; float f; } x; x.u = (uint32_t)u << 16; return x.f;
}

DEV float siluf(float x) { return x / (1.f + expf(-x)); }

// single-instruction exp2 (v_exp_f32); fallback keeps it compiling anywhere
DEV float fexp2(float x) {
#if __has_builtin(__builtin_amdgcn_exp2f)
  return __builtin_amdgcn_exp2f(x);
#else
  return exp2f(x);
#endif
}

#define BAR asm volatile("s_barrier" ::: "memory")
#define LGKM0 do { asm volatile("s_waitcnt lgkmcnt(0)" ::: "memory"); \
                   __builtin_amdgcn_sched_barrier(0); } while (0)
#define VMCNT(n) asm volatile("s_waitcnt vmcnt(" #n ")" ::: "memory")

// ---------------- sentinel fill (diagnostic) ----------------------------------
__global__ __launch_bounds__(256) void fill_kernel(float* p, float v, int n) {
  int i = blockIdx.x * 256 + threadIdx.x;
  if (i < n) p[i] = v;
}

// ---------------- f32 -> bf16 convert (with zero tail padding) ---------------
__global__ __launch_bounds__(256) void cvt_bf16_kernel(const float* __restrict__ src,
                                                       ushort_t* __restrict__ dst,
                                                       int n_src4, int n_dst4) {
  int i = blockIdx.x * 256 + threadIdx.x;
  if (i >= n_dst4) return;
  f32x4 v;
  if (i < n_src4) v = *(const f32x4*)(src + (size_t)i * 4);
  else { v.x = 0.f; v.y = 0.f; v.z = 0.f; v.w = 0.f; }
  u16x4 o;
  o.x = f2bf(v.x); o.y = f2bf(v.y); o.z = f2bf(v.z); o.w = f2bf(v.w);
  *(u16x4*)(dst + (size_t)i * 4) = o;
}

// ================= 256x256 8-phase bf16 GEMM (T2+T3+T4+T5) ====================
// R14: coalesced epilogue — C tile staged in the (now free) 128KB LDS, then
// streamed out as 16B vector stores (MODE 0: uniform gate/xbc dest per block
// since the col-4096 split is tile-aligned; MODE 1: two 128-row halves).
DEV void ld_a4(const unsigned char* ab2, int mgofs, int ck0, int ck1, bf16x8 (&af)[4][2]) {
#pragma unroll
  for (int mi = 0; mi < 4; ++mi) {
    const unsigned char* p = ab2 + (mgofs + mi * 16) * 128;
    af[mi][0] = *(const bf16x8*)(p + ck0);
    af[mi][1] = *(const bf16x8*)(p + ck1);
  }
}

DEV void ld_b2(const unsigned char* bb2, int npofs, int ck0, int ck1, bf16x8 (&bf)[2][2]) {
#pragma unroll
  for (int ni = 0; ni < 2; ++ni) {
    const unsigned char* p = bb2 + (npofs + ni * 16) * 128;
    bf[ni][0] = *(const bf16x8*)(p + ck0);
    bf[ni][1] = *(const bf16x8*)(p + ck1);
  }
}

DEV void mm16(f32x4 (&acc)[8][4], const bf16x8 (&af)[4][2], const bf16x8 (&bf)[2][2],
              int mb, int nb) {
  __builtin_amdgcn_s_setprio(1);
#pragma unroll
  for (int mi = 0; mi < 4; ++mi)
#pragma unroll
    for (int ni = 0; ni < 2; ++ni)
#pragma unroll
      for (int kk = 0; kk < 2; ++kk)
        acc[mb + mi][nb + ni] = __builtin_amdgcn_mfma_f32_16x16x32_bf16(
            af[mi][kk], bf[ni][kk], acc[mb + mi][nb + ni], 0, 0, 0);
  __builtin_amdgcn_s_setprio(0);
}

DEV void stage2(const ushort_t* s0, const ushort_t* s1, unsigned char* d) {
  gload_lds16(s0, d);
  gload_lds16(s1, d + 8192);
}

template <int MODE>
__global__ __launch_bounds__(512, 1) void gemm8_kernel(const ushort_t* __restrict__ A,
                                                       const ushort_t* __restrict__ B,
                                                       void* __restrict__ C0,
                                                       void* __restrict__ C1,
                                                       int K, int NB, int NC, int niter) {
  __shared__ __align__(16) unsigned char lds[131072];
  const int tid = threadIdx.x;
  const int l = tid & 63, w = tid >> 6;
  const int wr = w >> 2, wc = w & 3;
  const int lr = l & 15, lk = l >> 4;
  const int xm = (lr & 7) << 4;
  const int ck0 = (lk * 16) ^ xm;
  const int ck1 = (64 + lk * 16) ^ xm;
  const int bm = blockIdx.x, bn = blockIdx.y;

  const int rr = (w << 3) + (l >> 3);
  const int cE = ((l & 7) ^ (l >> 3)) << 3;
  const int dstoff = w * 1024 + l * 16;

  const ushort_t* sA00 = A + (size_t)(bm * 256 +       rr) * K + cE;
  const ushort_t* sA01 = A + (size_t)(bm * 256 +  64 + rr) * K + cE;
  const ushort_t* sA10 = A + (size_t)(bm * 256 + 128 + rr) * K + cE;
  const ushort_t* sA11 = A + (size_t)(bm * 256 + 192 + rr) * K + cE;
  int rb0 = bn * 256 +       rr; if (rb0 > NB - 1) rb0 = NB - 1;
  int rb1 = bn * 256 +  64 + rr; if (rb1 > NB - 1) rb1 = NB - 1;
  int rb2 = bn * 256 + 128 + rr; if (rb2 > NB - 1) rb2 = NB - 1;
  int rb3 = bn * 256 + 192 + rr; if (rb3 > NB - 1) rb3 = NB - 1;
  const ushort_t* sB00 = B + (size_t)rb0 * K + cE;
  const ushort_t* sB01 = B + (size_t)rb1 * K + cE;
  const ushort_t* sB10 = B + (size_t)rb2 * K + cE;
  const ushort_t* sB11 = B + (size_t)rb3 * K + cE;

  const int aoff = wr * 16384 + lr * 128;
  const int boff = 32768 + (wc >> 1) * 16384 + ((wc & 1) * 64 + lr) * 128;

  f32x4 acc[8][4] = {};
  bf16x8 af[4][2], bf[2][2], bg[2][2];

  stage2(sA00, sA01, lds + dstoff);
  stage2(sA10, sA11, lds + 16384 + dstoff);
  stage2(sB00, sB01, lds + 32768 + dstoff);
  stage2(sB10, sB11, lds + 49152 + dstoff);
  stage2(sA00 + 64, sA01 + 64, lds + 65536 + dstoff);
  VMCNT(2);
  BAR;

  auto kpair = [&](int kt0, bool last) {
    const unsigned char* a0 = lds + aoff;
    const unsigned char* b0 = lds + boff;
    const unsigned char* a1 = lds + 65536 + aoff;
    const unsigned char* b1 = lds + 65536 + boff;
    const size_t c1 = (size_t)(kt0 + 1) * 64;
    const size_t c2 = (size_t)(kt0 + 2) * 64;
    const size_t c3 = (size_t)(kt0 + 3) * 64;
    ld_a4(a0, 0, ck0, ck1, af);
    ld_b2(b0, 0, ck0, ck1, bf);
    stage2(sA10 + c1, sA11 + c1, lds + 65536 + 16384 + dstoff);
    BAR; LGKM0; mm16(acc, af, bf, 0, 0); BAR;
    ld_b2(b0, 32, ck0, ck1, bg);
    stage2(sB00 + c1, sB01 + c1, lds + 65536 + 32768 + dstoff);
    BAR; LGKM0; mm16(acc, af, bg, 0, 2); BAR;
    ld_a4(a0, 64, ck0, ck1, af);
    stage2(sB10 + c1, sB11 + c1, lds + 65536 + 49152 + dstoff);
    BAR; LGKM0; mm16(acc, af, bg, 4, 2); BAR;
    if (!last) { stage2(sA00 + c2, sA01 + c2, lds + dstoff); VMCNT(2); }
    else       { VMCNT(0); }
    BAR; LGKM0; mm16(acc, af, bf, 4, 0); BAR;
    ld_a4(a1, 0, ck0, ck1, af);
    ld_b2(b1, 0, ck0, ck1, bf);
    if (!last) stage2(sA10 + c2, sA11 + c2, lds + 16384 + dstoff);
    BAR; LGKM0; mm16(acc, af, bf, 0, 0); BAR;
    ld_b2(b1, 32, ck0, ck1, bg);
    if (!last) stage2(sB00 + c2, sB01 + c2, lds + 32768 + dstoff);
    BAR; LGKM0; mm16(acc, af, bg, 0, 2); BAR;
    ld_a4(a1, 64, ck0, ck1, af);
    if (!last) stage2(sB10 + c2, sB11 + c2, lds + 49152 + dstoff);
    BAR; LGKM0; mm16(acc, af, bg, 4, 2); BAR;
    if (!last) { stage2(sA00 + c3, sA01 + c3, lds + 65536 + dstoff); VMCNT(2); }
    BAR; LGKM0; mm16(acc, af, bf, 4, 0); BAR;
  };

  for (int it = 0; it < niter - 1; ++it) kpair(2 * it, false);
  kpair(2 * (niter - 1), true);
  // main loop done; final BAR above means every wave's LDS reads retired.

  if (MODE == 0) {
    // ---- acc -> LDS bf16 [256 rows][512B], swz cb ^= (row&7)<<4 ----
#pragma unroll
    for (int mi = 0; mi < 8; ++mi)
#pragma unroll
      for (int ni = 0; ni < 4; ++ni)
#pragma unroll
        for (int r = 0; r < 4; ++r) {
          const int row = wr * 128 + mi * 16 + (lk << 2) + r;
          const int cb = (wc * 64 + ni * 16 + lr) * 2;
          *(ushort_t*)(lds + row * 512 + (cb ^ ((row & 7) << 4))) =
              f2bf(acc[mi][ni][r]);
        }
    LGKM0; BAR;
    // ---- stream out: half-wave per 512B row, u16x8 stores (coalesced) ----
    ushort_t* dstb; size_t stride; int cbase;
    if (bn < 16) { dstb = (ushort_t*)C0; stride = 4096; cbase = bn * 256; }
    else         { dstb = (ushort_t*)C1; stride = 6272; cbase = bn * 256 - 4096; }
    const int lc = l & 31;
    const bool okc = (bn * 256 + lc * 8) < NC;
#pragma unroll
    for (int it = 0; it < 16; ++it) {
      const int row = w * 32 + it * 2 + (l >> 5);
      u16x8 v = *(const u16x8*)(lds + row * 512 + ((lc * 16) ^ ((row & 7) << 4)));
      if (okc)
        *(u16x8*)(dstb + (size_t)(bm * 256 + row) * stride + cbase + lc * 8) = v;
    }
  } else {
    // ---- f32 out in two 128-row halves: LDS [128][1024B], swz (rl&7)<<4 ----
    float* o = (float*)C0;
    const bool okc = (bn * 256 + l * 4) < NC;
#pragma unroll
    for (int h2 = 0; h2 < 2; ++h2) {
      if (h2) { LGKM0; BAR; }          // prior half's reads done before overwrite
      if (wr == h2) {
#pragma unroll
        for (int mi = 0; mi < 8; ++mi)
#pragma unroll
          for (int ni = 0; ni < 4; ++ni)
#pragma unroll
            for (int r = 0; r < 4; ++r) {
              const int rl = mi * 16 + (lk << 2) + r;
              const int cb = (wc * 64 + ni * 16 + lr) * 4;
              *(float*)(lds + rl * 1024 + (cb ^ ((rl & 7) << 4))) = acc[mi][ni][r];
            }
      }
      LGKM0; BAR;
#pragma unroll
      for (int it = 0; it < 16; ++it) {
        const int rl = w * 16 + it;
        f32x4 v = *(const f32x4*)(lds + rl * 1024 + ((l * 16) ^ ((rl & 7) << 4)));
        if (okc)
          *(f32x4*)(o + (size_t)(bm * 256 + h2 * 128 + rl) * NC + bn * 256 + l * 4) = v;
      }
    }
  }
}

// ---------------- causal depthwise conv (K=4) + bias + SiLU, bf16 in/out ------
__global__ __launch_bounds__(256) void conv_silu_kernel(const ushort_t* __restrict__ xbc,
                                                        const float* __restrict__ cw,
                                                        const float* __restrict__ cb,
                                                        ushort_t* __restrict__ out) {
  int idx = blockIdx.x * 256 + threadIdx.x;      // 4096*1536
  int c4 = (idx % 1536) << 2;
  int bt = idx / 1536;
  int t = bt & 2047;
  const ushort_t* base = xbc + (size_t)bt * 6272 + c4;
  f32x4 w0 = *(const f32x4*)&cw[(c4 + 0) * 4];
  f32x4 w1 = *(const f32x4*)&cw[(c4 + 1) * 4];
  f32x4 w2 = *(const f32x4*)&cw[(c4 + 2) * 4];
  f32x4 w3 = *(const f32x4*)&cw[(c4 + 3) * 4];
  f32x4 acc = *(const f32x4*)&cb[c4];
#pragma unroll
  for (int i = 0; i < 4; ++i) {
    int dt_ = i - 3;
    if (t + dt_ >= 0) {
      u16x4 xv = *(const u16x4*)(base + (ptrdiff_t)dt_ * 6272);
      acc.x += bf2f(xv.x) * w0[i];
      acc.y += bf2f(xv.y) * w1[i];
      acc.z += bf2f(xv.z) * w2[i];
      acc.w += bf2f(xv.w) * w3[i];
    }
  }
  u16x4 o;
  o.x = f2bf(siluf(acc.x)); o.y = f2bf(siluf(acc.y));
  o.z = f2bf(siluf(acc.z)); o.w = f2bf(siluf(acc.w));
  *(u16x4*)(out + (size_t)bt * 6144 + c4) = o;
}

// ---------------- dt: softplus + exp(A*dt), layout [H][2][BT] f32 -------------
__global__ __launch_bounds__(256) void dt_kernel(const ushort_t* __restrict__ xbc,
                                                 const float* __restrict__ dt_bias,
                                                 const float* __restrict__ Avec,
                                                 float* __restrict__ dtA) {
  int idx = blockIdx.x * 256 + threadIdx.x;      // 64*4096
  int h = idx >> 12, bt = idx & 4095;
  float v = bf2f(xbc[(size_t)bt * 6272 + 6144 + h]) + dt_bias[h];
  float sp = fmaxf(v, 0.f) + log1pf(expf(-fabsf(v)));
  float ab = expf(Avec[h] * sp);
  dtA[(h << 13) + bt] = sp;
  dtA[(h << 13) + 4096 + bt] = ab;
}

// ---------------- SSD chunk kernel (R13 version, unchanged) -------------------
__global__ __launch_bounds__(256) void ssd_kernel(const ushort_t* __restrict__ conv,
                                                  const float* __restrict__ dtA,
                                                  const float* __restrict__ Dvec,
                                                  const float* __restrict__ Avec,
                                                  ushort_t* __restrict__ yssm,
                                                  ushort_t* __restrict__ hst,
                                                  float* __restrict__ abprod) {
  const int bid = blockIdx.x;
  const int ck = bid & 7;
  const int h = (bid >> 3) & 63;
  const int b = bid >> 9;
  const int g = h >> 3;
  const int tid = threadIdx.x;
  const int lane = tid & 63;
  const int wv = tid >> 6;
  const int lr = lane & 15, lk = lane >> 4;
  const int btb = (b << 11) + (ck << 8);

  __shared__ __align__(16) unsigned char ldsb[69648];
  float* csL = (float*)(ldsb + 65536);
  float* dtL = (float*)(ldsb + 66560);
  float* wL  = (float*)(ldsb + 67584);
  float* l2L = (float*)(ldsb + 68608);
  float* wsum = (float*)(ldsb + 69632);

  const float Ah = Avec[h];
  const float Dh = Dvec[h];
  const float AhL2 = Ah * 1.44269504f;

  // ---- Ph0: inclusive cumsum of dt ----
  float dv = dtA[(h << 13) + btb + tid];
  float s = dv;
#pragma unroll
  for (int off = 1; off < 64; off <<= 1) {
    float t = __shfl_up(s, off, 64);
    if (lane >= off) s += t;
  }
  if (lane == 63) wsum[wv] = s;
  __syncthreads();
  float basev = 0.f;
  for (int i = 0; i < wv; ++i) basev += wsum[i];
  const float csv = basev + s;
  csL[tid] = csv;
  dtL[tid] = dv;
  l2L[tid] = AhL2 * csv;
  __syncthreads();
  const float cstot = csL[255];
  wL[tid] = dv * fexp2(AhL2 * (cstot - csv));
  if (tid == 0) abprod[((b << 6) + h) * 8 + ck] = expf(Ah * cstot);

  // ---- Ph1: XT build via coalesced column gather + vectorized writes ----
  const ushort_t* Xg = conv + (size_t)btb * 6144 + (h << 6);
  {
    const int p = lane;
#pragma unroll
    for (int rep = 0; rep < 8; ++rep) {
      const int t0 = (rep * 4 + wv) << 3;
      u16x8 v;
#pragma unroll
      for (int k = 0; k < 8; ++k) v[k] = Xg[(size_t)(t0 + k) * 6144 + p];
      *(u16x8*)(ldsb + p * 512 + ((t0 * 2) ^ ((p & 15) << 4))) = v;
    }
  }
  __syncthreads();   // XT + wL visible

  // ---- Ph2: hst = XT * BwT^T, t in two halves of 128 (BwT in scratch) ----
  const ushort_t* Bg = conv + (size_t)btb * 6144 + 4096 + (g << 7);
  f32x4 hacc[4][2] = {};
  for (int th = 0; th < 2; ++th) {
#pragma unroll
    for (int rep = 0; rep < 8; ++rep) {
      const int n = ((rep & 1) << 6) | lane;
      const int tl0 = ((rep >> 1) * 4 + wv) << 3;        // within-half t
      const int t0 = th * 128 + tl0;
      u16x8 v;
#pragma unroll
      for (int k = 0; k < 8; ++k)
        v[k] = f2bf(bf2f(Bg[(size_t)(t0 + k) * 6144 + n]) * wL[t0 + k]);
      *(u16x8*)(ldsb + 32768 + n * 256 + ((tl0 * 2) ^ ((n & 15) << 4))) = v;
    }
    __syncthreads();
#pragma unroll
    for (int tc = 0; tc < 4; ++tc) {
      bf16x8 a4[4], b2[2];
#pragma unroll
      for (int pf = 0; pf < 4; ++pf) {
        const int p = pf * 16 + lr;
        a4[pf] = *(const bf16x8*)(ldsb + p * 512 +
                                  (((th * 128 + tc * 32 + lk * 8) * 2) ^ ((p & 15) << 4)));
      }
#pragma unroll
      for (int nf = 0; nf < 2; ++nf) {
        const int n = wv * 32 + nf * 16 + lr;
        b2[nf] = *(const bf16x8*)(ldsb + 32768 + n * 256 +
                                  (((tc * 32 + lk * 8) * 2) ^ ((n & 15) << 4)));
      }
#pragma unroll
      for (int pf = 0; pf < 4; ++pf)
#pragma unroll
        for (int nf = 0; nf < 2; ++nf)
          hacc[pf][nf] = __builtin_amdgcn_mfma_f32_16x16x32_bf16(a4[pf], b2[nf],
                                                                 hacc[pf][nf], 0, 0, 0);
    }
    __syncthreads();   // scratch free before next half / Ph3
  }
  // write hst (layout identical to prior rounds)
#pragma unroll
  for (int pf = 0; pf < 4; ++pf)
#pragma unroll
    for (int nf = 0; nf < 2; ++nf)
#pragma unroll
      for (int r = 0; r < 4; ++r) {
        int p = pf * 16 + (lk << 2) + r;
        int n = wv * 32 + nf * 16 + lr;
        hst[((size_t)((b << 10) | (h << 4) | ((p >> 5) << 3) | ck)) * 4096 +
            (size_t)(p & 31) * 128 + n] = f2bf(hacc[pf][nf][r]);
      }

  // ---- Ph3: per 64-row block: S -> mask -> P -> Y^T ----
  const ushort_t* Cg = conv + (size_t)btb * 6144 + 5120 + (g << 7);
  for (int rb = 0; rb < 4; ++rb) {
    const int i0 = rb << 6;
    f32x4 sacc[4][4] = {};
#pragma unroll
    for (int kk = 0; kk < 4; ++kk) {
      bf16x8 ca[4], bb[4];
#pragma unroll
      for (int ifr = 0; ifr < 4; ++ifr)
        ca[ifr] = *(const bf16x8*)(Cg + (size_t)(i0 + ifr * 16 + lr) * 6144 + kk * 32 + lk * 8);
#pragma unroll
      for (int jf = 0; jf < 4; ++jf)
        bb[jf] = *(const bf16x8*)(Bg + (size_t)(wv * 64 + jf * 16 + lr) * 6144 + kk * 32 + lk * 8);
#pragma unroll
      for (int ifr = 0; ifr < 4; ++ifr)
#pragma unroll
        for (int jf = 0; jf < 4; ++jf)
          sacc[ifr][jf] = __builtin_amdgcn_mfma_f32_16x16x32_bf16(ca[ifr], bb[jf],
                                                                  sacc[ifr][jf], 0, 0, 0);
    }
    // mask + write P (swz (il&15)<<4). Decay via single-instr exp2.
#pragma unroll
    for (int ifr = 0; ifr < 4; ++ifr) {
      const int ibmax = i0 + ifr * 16 + 15;
#pragma unroll
      for (int jf = 0; jf < 4; ++jf) {
        const int jbmin = wv * 64 + jf * 16;          // wave-uniform
        const int j = jbmin + lr;
        if (jbmin > ibmax) {
#pragma unroll
          for (int r = 0; r < 4; ++r) {
            int il = ifr * 16 + (lk << 2) + r;
            *(ushort_t*)(ldsb + 32768 + il * 512 + ((j * 2) ^ ((il & 15) << 4))) = 0;
          }
        } else {
          const float dtj = dtL[j];
          const float l2j = l2L[j];
#pragma unroll
          for (int r = 0; r < 4; ++r) {
            int il = ifr * 16 + (lk << 2) + r;
            int ig = i0 + il;
            float val = 0.f;
            if (j <= ig) val = sacc[ifr][jf][r] * dtj * fexp2(l2L[ig] - l2j);
            *(ushort_t*)(ldsb + 32768 + il * 512 + ((j * 2) ^ ((il & 15) << 4))) = f2bf(val);
          }
        }
      }
    }
    __syncthreads();
    // Y^T[p][i] = sum_j XT[p][j] * P[i][j]
    f32x4 yacc[4] = {};
    const int ilB = wv * 16 + lr;
#pragma unroll
    for (int ks = 0; ks < 8; ++ks) {
      bf16x8 pb = *(const bf16x8*)(ldsb + 32768 + ilB * 512 +
                                   (((ks * 32 + lk * 8) * 2) ^ ((ilB & 15) << 4)));
#pragma unroll
      for (int pf = 0; pf < 4; ++pf) {
        const int p = pf * 16 + lr;
        bf16x8 pa = *(const bf16x8*)(ldsb + p * 512 +
                                     (((ks * 32 + lk * 8) * 2) ^ ((p & 15) << 4)));
        yacc[pf] = __builtin_amdgcn_mfma_f32_16x16x32_bf16(pa, pb, yacc[pf], 0, 0, 0);
      }
    }
    // epilogue: + D*x, write yssm
    const int irow = i0 + wv * 16 + lr;
    const size_t ybase = (size_t)(btb + irow) * 4096 + (h << 6);
#pragma unroll
    for (int pf = 0; pf < 4; ++pf) {
      u16x4 o;
#pragma unroll
      for (int r = 0; r < 4; ++r) {
        int p = pf * 16 + (lk << 2) + r;
        float xv = bf2f(*(const ushort_t*)(ldsb + p * 512 +
                                           ((irow * 2) ^ ((p & 15) << 4))));
        o[r] = f2bf(yacc[pf][r] + Dh * xv);
      }
      *(u16x4*)(yssm + ybase + pf * 16 + (lk << 2)) = o;
    }
    __syncthreads();   // protect P before next rb overwrites it
  }
}

// ---------------- combine: prefix over chunk states (in place) ----------------
__global__ __launch_bounds__(256) void combine_kernel(ushort_t* __restrict__ hst,
                                                      const float* __restrict__ abprod) {
  const int bid = blockIdx.x;
  const int bh = bid >> 1;
  const int tid = threadIdx.x;
  const size_t base = (size_t)bid * 8 * 4096 + tid * 16;
  float hrun[16];
#pragma unroll
  for (int e = 0; e < 16; ++e) hrun[e] = 0.f;
  for (int c = 0; c < 8; ++c) {
    const size_t p = base + (size_t)c * 4096;
    u16x8 v0 = *(const u16x8*)&hst[p];
    u16x8 v1 = *(const u16x8*)&hst[p + 8];
    float ab = abprod[bh * 8 + c];
    u16x8 w0, w1;
#pragma unroll
    for (int e = 0; e < 8; ++e) { w0[e] = f2bf(hrun[e]); w1[e] = f2bf(hrun[8 + e]); }
    *(u16x8*)&hst[p] = w0;
    *(u16x8*)&hst[p + 8] = w1;
#pragma unroll
    for (int e = 0; e < 8; ++e) {
      hrun[e] = ab * hrun[e] + bf2f(v0[e]);
      hrun[8 + e] = ab * hrun[8 + e] + bf2f(v1[e]);
    }
  }
}

// ---------------- correction: yssm += pd[t] * (C_t . H_init) ------------------
__global__ __launch_bounds__(256) void correct_kernel(const ushort_t* __restrict__ conv,
                                                      const float* __restrict__ dtA,
                                                      const float* __restrict__ Avec,
                                                      const ushort_t* __restrict__ hst,
                                                      ushort_t* __restrict__ yssm) {
  const int bid = blockIdx.x;
  const int ck = bid & 7;
  const int h = (bid >> 3) & 63;
  const int b = bid >> 9;
  const int g = h >> 3;
  const int tid = threadIdx.x;
  const int lane = tid & 63;
  const int w = tid >> 6;
  const int lr = lane & 15, lk = lane >> 4;
  const int btb = (b << 11) + (ck << 8);

  __shared__ float pdl[256];
  __shared__ float wsum[4];
  float s = dtA[(h << 13) + btb + tid];
#pragma unroll
  for (int off = 1; off < 64; off <<= 1) {
    float t = __shfl_up(s, off, 64);
    if (lane >= off) s += t;
  }
  if (lane == 63) wsum[w] = s;
  __syncthreads();
  float basev = 0.f;
  for (int i = 0; i < w; ++i) basev += wsum[i];
  pdl[tid] = expf(Avec[h] * (basev + s));
  __syncthreads();

  const ushort_t* Cc = conv + (size_t)btb * 6144 + 5120 + (g << 7);
  const size_t hb0 = ((size_t)((b << 10) | (h << 4) | (0 << 3) | ck)) * 4096;
  const size_t hb1 = ((size_t)((b << 10) | (h << 4) | (1 << 3) | ck)) * 4096;

  f32x4 acc[4][4] = {};
#pragma unroll
  for (int kk = 0; kk < 4; ++kk) {
    const int k0 = kk * 32 + lk * 8;
    bf16x8 afr[4], bfr[4];
#pragma unroll
    for (int mf = 0; mf < 4; ++mf) {
      const int t = w * 64 + mf * 16 + lr;
      afr[mf] = *(const bf16x8*)(Cc + (size_t)t * 6144 + k0);
    }
#pragma unroll
    for (int nf = 0; nf < 4; ++nf) {
      const int p = nf * 16 + lr;
      const size_t hb = (p < 32) ? hb0 : hb1;
      bfr[nf] = *(const bf16x8*)(hst + hb + (size_t)(p & 31) * 128 + k0);
    }
#pragma unroll
    for (int mf = 0; mf < 4; ++mf)
#pragma unroll
      for (int nf = 0; nf < 4; ++nf)
        acc[mf][nf] = __builtin_amdgcn_mfma_f32_16x16x32_bf16(afr[mf], bfr[nf],
                                                              acc[mf][nf], 0, 0, 0);
  }

#pragma unroll
  for (int mf = 0; mf < 4; ++mf) {
#pragma unroll
    for (int r = 0; r < 4; ++r) {
      const int row = w * 64 + mf * 16 + (lk << 2) + r;
      const float pd = pdl[row];
      const size_t yrow = (size_t)(btb + row) * 4096 + (h << 6);
#pragma unroll
      for (int nf = 0; nf < 4; ++nf) {
        const int p = nf * 16 + lr;
        const size_t idx = yrow + p;
        yssm[idx] = f2bf(bf2f(yssm[idx]) + pd * acc[mf][nf][r]);
      }
    }
  }
}

// ---------------- gate * silu + RMSNorm -> bf16 -------------------------------
__global__ __launch_bounds__(256) void norm_kernel(const ushort_t* __restrict__ yssm,
                                                   const ushort_t* __restrict__ gate,
                                                   const float* __restrict__ nw,
                                                   ushort_t* __restrict__ out) {
  const int bt = blockIdx.x;
  const int tid = threadIdx.x;
  const ushort_t* y = yssm + (size_t)bt * 4096;
  const ushort_t* gt = gate + (size_t)bt * 4096;
  float vals[16];
  float ss = 0.f;
#pragma unroll
  for (int j = 0; j < 4; ++j) {
    int o = (tid + j * 256) << 2;
    u16x4 yv = *(const u16x4*)(y + o);
    u16x4 gv = *(const u16x4*)(gt + o);
#pragma unroll
    for (int e = 0; e < 4; ++e) {
      float v = bf2f(yv[e]) * siluf(bf2f(gv[e]));
      vals[j * 4 + e] = v;
      ss += v * v;
    }
  }
#pragma unroll
  for (int m = 1; m <= 32; m <<= 1) ss += __shfl_xor(ss, m, 64);
  __shared__ float red[4];
  if ((tid & 63) == 0) red[tid >> 6] = ss;
  __syncthreads();
  ss = red[0] + red[1] + red[2] + red[3];
  const float sc = rsqrtf(ss * (1.f / 4096.f) + 1e-5f);
#pragma unroll
  for (int j = 0; j < 4; ++j) {
    int o = (tid + j * 256) << 2;
    f32x4 wv = *(const f32x4*)(nw + o);
    u16x4 ov;
    ov.x = f2bf(vals[j * 4 + 0] * sc * wv.x);
    ov.y = f2bf(vals[j * 4 + 1] * sc * wv.y);
    ov.z = f2bf(vals[j * 4 + 2] * sc * wv.z);
    ov.w = f2bf(vals[j * 4 + 3] * sc * wv.w);
    *(u16x4*)(out + (size_t)bt * 4096 + o) = ov;
  }
}

// ------------------------------------------------------------------------------
extern "C" void kernel_launch(void* const* d_in, const int* in_sizes, int n_in,
                              void* d_out, int out_size, void* d_ws, size_t ws_size,
                              hipStream_t stream) {
  const float* hidden  = (const float*)d_in[0];
  const float* w_in    = (const float*)d_in[1];
  const float* conv_w  = (const float*)d_in[2];
  const float* conv_b  = (const float*)d_in[3];
  const float* Avec    = (const float*)d_in[4];
  const float* Dvec    = (const float*)d_in[5];
  const float* dt_bias = (const float*)d_in[6];
  const float* nw      = (const float*)d_in[7];
  const float* w_out   = (const float*)d_in[8];
  float* out = (float*)d_out;

  char* ws = (char*)d_ws;
  // Region map (total 162,693,120 B) — unchanged since R4.
  ushort_t* Xbf   = (ushort_t*)(ws);
  ushort_t* W1bf  = (ushort_t*)(ws + 22020096);
  ushort_t* gate  = (ushort_t*)(ws + 77758464);
  ushort_t* xbc   = (ushort_t*)(ws + 111312896);
  ushort_t* W2bf  = Xbf;
  ushort_t* convb = W1bf;
  float*    dtA   = (float*)(ws + 22020096 + 50331648);
  float*    abprod= (float*)(ws + 22020096 + 52428800);
  ushort_t* yssm  = xbc;
  ushort_t* hst   = (ushort_t*)(ws + 111312896 + 33554432);
  ushort_t* ynorm = convb;
  const size_t NEED = 162693120;
  if (NEED > ws_size) {
    fill_kernel<<<4, 256, 0, stream>>>(out, 12345.0f, 1024);   // sentinel: ws too small
    return;
  }

  cvt_bf16_kernel<<<10752, 256, 0, stream>>>(hidden, Xbf, 2752512, 2752512);
  cvt_bf16_kernel<<<27216, 256, 0, stream>>>(w_in, W1bf, 6924288, 6967296);
  gemm8_kernel<0><<<dim3(16, 41), 512, 0, stream>>>(Xbf, W1bf, gate, xbc,
                                                    2688, 10368, 10304, 21);
  cvt_bf16_kernel<<<10752, 256, 0, stream>>>(w_out, W2bf, 2752512, 2752512);
  conv_silu_kernel<<<24576, 256, 0, stream>>>(xbc, conv_w, conv_b, convb);
  dt_kernel<<<1024, 256, 0, stream>>>(xbc, dt_bias, Avec, dtA);
  ssd_kernel<<<1024, 256, 0, stream>>>(convb, dtA, Dvec, Avec, yssm, hst, abprod);
  combine_kernel<<<256, 256, 0, stream>>>(hst, abprod);
  correct_kernel<<<1024, 256, 0, stream>>>(convb, dtA, Avec, hst, yssm);
  norm_kernel<<<4096, 256, 0, stream>>>(yssm, gate, nw, ynorm);
  gemm8_kernel<1><<<dim3(16, 11), 512, 0, stream>>>(ynorm, W2bf, out, nullptr,
                                                    4096, 2688, 2688, 32);
}

// Round 15
// 657.521 us; speedup vs baseline: 1.1390x; 1.0011x over previous
//
#include <hip/hip_runtime.h>
#include <stdint.h>

typedef unsigned short ushort_t;
typedef __attribute__((ext_vector_type(4))) float f32x4;
typedef __attribute__((ext_vector_type(2))) float f32x2;
typedef __attribute__((ext_vector_type(8))) __bf16 bf16x8;
typedef __attribute__((ext_vector_type(4))) unsigned short u16x4;
typedef __attribute__((ext_vector_type(8))) unsigned short u16x8;

#define DEV __device__ __forceinline__

// async global->LDS, 16B per lane. HW: dest = wave-uniform base + laneID*16.
DEV void gload_lds16(const void* g, void* l) {
  __builtin_amdgcn_global_load_lds(
      (const __attribute__((address_space(1))) uint32_t*)(uintptr_t)(g),
      (__attribute__((address_space(3))) uint32_t*)(uintptr_t)(l), 16, 0, 0);
}

DEV ushort_t f2bf(float f) {
  union { float f; uint32_t u; } x; x.f = f;
  x.u += 0x7fffu + ((x.u >> 16) & 1u);   // RNE
  return (ushort_t)(x.u >> 16);
}

DEV float bf2f(ushort_t u) {
  union { uint32_t u; float f; } x; x.u = (uint32_t)u << 16; return x.f;
}

DEV float siluf(float x) { return x / (1.f + expf(-x)); }

// single-instruction exp2 (v_exp_f32); fallback keeps it compiling anywhere
DEV float fexp2(float x) {
#if __has_builtin(__builtin_amdgcn_exp2f)
  return __builtin_amdgcn_exp2f(x);
#else
  return exp2f(x);
#endif
}

#define BAR asm volatile("s_barrier" ::: "memory")
#define LGKM0 do { asm volatile("s_waitcnt lgkmcnt(0)" ::: "memory"); \
                   __builtin_amdgcn_sched_barrier(0); } while (0)
#define VMCNT(n) asm volatile("s_waitcnt vmcnt(" #n ")" ::: "memory")

// ---------------- sentinel fill (diagnostic) ----------------------------------
__global__ __launch_bounds__(256) void fill_kernel(float* p, float v, int n) {
  int i = blockIdx.x * 256 + threadIdx.x;
  if (i < n) p[i] = v;
}

// ---------------- f32 -> bf16 convert (with zero tail padding) ---------------
__global__ __launch_bounds__(256) void cvt_bf16_kernel(const float* __restrict__ src,
                                                       ushort_t* __restrict__ dst,
                                                       int n_src4, int n_dst4) {
  int i = blockIdx.x * 256 + threadIdx.x;
  if (i >= n_dst4) return;
  f32x4 v;
  if (i < n_src4) v = *(const f32x4*)(src + (size_t)i * 4);
  else { v.x = 0.f; v.y = 0.f; v.z = 0.f; v.w = 0.f; }
  u16x4 o;
  o.x = f2bf(v.x); o.y = f2bf(v.y); o.z = f2bf(v.z); o.w = f2bf(v.w);
  *(u16x4*)(dst + (size_t)i * 4) = o;
}

// ================= 256x256 4-phase bf16 GEMM ==================================
// R15: 8->4 phases per kpair (32 MFMA/phase). Wave holds B-FULL in regs across
// both q-phases of a tile (no B reload); barriers halved (16->8 per kpair).
// Staging ledger (periodic): F1 stages s1.A; F2 stages s0'.B + vmcnt(4)
// (drains s1's 8); F3 stages s0'.A; F4 stages s1'.B + vmcnt(4) (drains s0').
// WAR: A region free after F2/F4 barrier; B region free after F1/F3 barrier
// (B reg-resident in q1). Prologue: s0.A+s0.B+s1.B, vmcnt(4). Last kpair:
// F2 vmcnt(0), F3/F4 no stages.
DEV void ld_a4(const unsigned char* ab2, int mgofs, int ck0, int ck1, bf16x8 (&af)[4][2]) {
#pragma unroll
  for (int mi = 0; mi < 4; ++mi) {
    const unsigned char* p = ab2 + (mgofs + mi * 16) * 128;
    af[mi][0] = *(const bf16x8*)(p + ck0);
    af[mi][1] = *(const bf16x8*)(p + ck1);
  }
}

DEV void ld_b2(const unsigned char* bb2, int npofs, int ck0, int ck1, bf16x8 (&bf)[2][2]) {
#pragma unroll
  for (int ni = 0; ni < 2; ++ni) {
    const unsigned char* p = bb2 + (npofs + ni * 16) * 128;
    bf[ni][0] = *(const bf16x8*)(p + ck0);
    bf[ni][1] = *(const bf16x8*)(p + ck1);
  }
}

DEV void mm32(f32x4 (&acc)[8][4], const bf16x8 (&af)[4][2], const bf16x8 (&bl)[2][2],
              const bf16x8 (&bh)[2][2], int mb) {
  __builtin_amdgcn_s_setprio(1);
#pragma unroll
  for (int mi = 0; mi < 4; ++mi)
#pragma unroll
    for (int kk = 0; kk < 2; ++kk) {
#pragma unroll
      for (int ni = 0; ni < 2; ++ni)
        acc[mb + mi][ni] = __builtin_amdgcn_mfma_f32_16x16x32_bf16(
            af[mi][kk], bl[ni][kk], acc[mb + mi][ni], 0, 0, 0);
#pragma unroll
      for (int ni = 0; ni < 2; ++ni)
        acc[mb + mi][2 + ni] = __builtin_amdgcn_mfma_f32_16x16x32_bf16(
            af[mi][kk], bh[ni][kk], acc[mb + mi][2 + ni], 0, 0, 0);
    }
  __builtin_amdgcn_s_setprio(0);
}

DEV void stage2(const ushort_t* s0, const ushort_t* s1, unsigned char* d) {
  gload_lds16(s0, d);
  gload_lds16(s1, d + 8192);
}

template <int MODE>
__global__ __launch_bounds__(512, 1) void gemm8_kernel(const ushort_t* __restrict__ A,
                                                       const ushort_t* __restrict__ B,
                                                       void* __restrict__ C0,
                                                       void* __restrict__ C1,
                                                       int K, int NB, int NC, int niter) {
  __shared__ __align__(16) unsigned char lds[131072];
  const int tid = threadIdx.x;
  const int l = tid & 63, w = tid >> 6;
  const int wr = w >> 2, wc = w & 3;
  const int lr = l & 15, lk = l >> 4;
  const int xm = (lr & 7) << 4;
  const int ck0 = (lk * 16) ^ xm;
  const int ck1 = (64 + lk * 16) ^ xm;
  const int bm = blockIdx.x, bn = blockIdx.y;

  const int rr = (w << 3) + (l >> 3);
  const int cE = ((l & 7) ^ (l >> 3)) << 3;
  const int dstoff = w * 1024 + l * 16;

  const ushort_t* sA00 = A + (size_t)(bm * 256 +       rr) * K + cE;
  const ushort_t* sA01 = A + (size_t)(bm * 256 +  64 + rr) * K + cE;
  const ushort_t* sA10 = A + (size_t)(bm * 256 + 128 + rr) * K + cE;
  const ushort_t* sA11 = A + (size_t)(bm * 256 + 192 + rr) * K + cE;
  int rb0 = bn * 256 +       rr; if (rb0 > NB - 1) rb0 = NB - 1;
  int rb1 = bn * 256 +  64 + rr; if (rb1 > NB - 1) rb1 = NB - 1;
  int rb2 = bn * 256 + 128 + rr; if (rb2 > NB - 1) rb2 = NB - 1;
  int rb3 = bn * 256 + 192 + rr; if (rb3 > NB - 1) rb3 = NB - 1;
  const ushort_t* sB00 = B + (size_t)rb0 * K + cE;
  const ushort_t* sB01 = B + (size_t)rb1 * K + cE;
  const ushort_t* sB10 = B + (size_t)rb2 * K + cE;
  const ushort_t* sB11 = B + (size_t)rb3 * K + cE;

  const int aoff = wr * 16384 + lr * 128;
  const int boff = 32768 + (wc >> 1) * 16384 + ((wc & 1) * 64 + lr) * 128;

  f32x4 acc[8][4] = {};
  bf16x8 af[4][2], bfl[2][2], bfh[2][2];

  // prologue: s0.A, s0.B, s1.B staged; drain s0 (8 oldest); barrier
  stage2(sA00, sA01, lds + dstoff);                      // s0.Ah0
  stage2(sA10, sA11, lds + 16384 + dstoff);              // s0.Ah1
  stage2(sB00, sB01, lds + 32768 + dstoff);              // s0.Bh0
  stage2(sB10, sB11, lds + 49152 + dstoff);              // s0.Bh1
  stage2(sB00 + 64, sB01 + 64, lds + 65536 + 32768 + dstoff);  // s1.Bh0
  stage2(sB10 + 64, sB11 + 64, lds + 65536 + 49152 + dstoff);  // s1.Bh1
  VMCNT(4);
  BAR;

  auto kpair = [&](int kt0, bool last) {
    const unsigned char* a0 = lds + aoff;
    const unsigned char* b0 = lds + boff;
    const unsigned char* a1 = lds + 65536 + aoff;
    const unsigned char* b1 = lds + 65536 + boff;
    const size_t c1 = (size_t)(kt0 + 1) * 64;
    const size_t c2 = (size_t)(kt0 + 2) * 64;
    const size_t c3 = (size_t)(kt0 + 3) * 64;
    // F1: s0 q0 (A rows 0..63 of wave-half + B full); stage s1.A
    ld_a4(a0, 0, ck0, ck1, af);
    ld_b2(b0, 0, ck0, ck1, bfl);
    ld_b2(b0, 32, ck0, ck1, bfh);
    stage2(sA00 + c1, sA01 + c1, lds + 65536 + dstoff);
    stage2(sA10 + c1, sA11 + c1, lds + 65536 + 16384 + dstoff);
    BAR; LGKM0; mm32(acc, af, bfl, bfh, 0); BAR;
    // F2: s0 q1 (A rows 64..127); stage s0'.B; DRAIN slot1 before barrier
    ld_a4(a0, 64, ck0, ck1, af);
    if (!last) {
      stage2(sB00 + c2, sB01 + c2, lds + 32768 + dstoff);
      stage2(sB10 + c2, sB11 + c2, lds + 49152 + dstoff);
      VMCNT(4);
    } else {
      VMCNT(0);
    }
    BAR; LGKM0; mm32(acc, af, bfl, bfh, 4); BAR;
    // F3: s1 q0 (A + B full); stage s0'.A
    ld_a4(a1, 0, ck0, ck1, af);
    ld_b2(b1, 0, ck0, ck1, bfl);
    ld_b2(b1, 32, ck0, ck1, bfh);
    if (!last) {
      stage2(sA00 + c2, sA01 + c2, lds + dstoff);
      stage2(sA10 + c2, sA11 + c2, lds + 16384 + dstoff);
    }
    BAR; LGKM0; mm32(acc, af, bfl, bfh, 0); BAR;
    // F4: s1 q1; stage s1'.B; DRAIN slot0' before barrier
    ld_a4(a1, 64, ck0, ck1, af);
    if (!last) {
      stage2(sB00 + c3, sB01 + c3, lds + 65536 + 32768 + dstoff);
      stage2(sB10 + c3, sB11 + c3, lds + 65536 + 49152 + dstoff);
      VMCNT(4);
    }
    BAR; LGKM0; mm32(acc, af, bfl, bfh, 4); BAR;
  };

  for (int it = 0; it < niter - 1; ++it) kpair(2 * it, false);
  kpair(2 * (niter - 1), true);
  // main loop done; final BAR above means every wave's LDS reads retired.

  if (MODE == 0) {
    // ---- acc -> LDS bf16 [256 rows][512B], swz cb ^= (row&7)<<4 ----
#pragma unroll
    for (int mi = 0; mi < 8; ++mi)
#pragma unroll
      for (int ni = 0; ni < 4; ++ni)
#pragma unroll
        for (int r = 0; r < 4; ++r) {
          const int row = wr * 128 + mi * 16 + (lk << 2) + r;
          const int cb = (wc * 64 + ni * 16 + lr) * 2;
          *(ushort_t*)(lds + row * 512 + (cb ^ ((row & 7) << 4))) =
              f2bf(acc[mi][ni][r]);
        }
    LGKM0; BAR;
    // ---- stream out: half-wave per 512B row, u16x8 stores (coalesced) ----
    ushort_t* dstb; size_t stride; int cbase;
    if (bn < 16) { dstb = (ushort_t*)C0; stride = 4096; cbase = bn * 256; }
    else         { dstb = (ushort_t*)C1; stride = 6272; cbase = bn * 256 - 4096; }
    const int lc = l & 31;
    const bool okc = (bn * 256 + lc * 8) < NC;
#pragma unroll
    for (int it = 0; it < 16; ++it) {
      const int row = w * 32 + it * 2 + (l >> 5);
      u16x8 v = *(const u16x8*)(lds + row * 512 + ((lc * 16) ^ ((row & 7) << 4)));
      if (okc)
        *(u16x8*)(dstb + (size_t)(bm * 256 + row) * stride + cbase + lc * 8) = v;
    }
  } else {
    // ---- f32 out in two 128-row halves: LDS [128][1024B], swz (rl&7)<<4 ----
    float* o = (float*)C0;
    const bool okc = (bn * 256 + l * 4) < NC;
#pragma unroll
    for (int h2 = 0; h2 < 2; ++h2) {
      if (h2) { LGKM0; BAR; }
      if (wr == h2) {
#pragma unroll
        for (int mi = 0; mi < 8; ++mi)
#pragma unroll
          for (int ni = 0; ni < 4; ++ni)
#pragma unroll
            for (int r = 0; r < 4; ++r) {
              const int rl = mi * 16 + (lk << 2) + r;
              const int cb = (wc * 64 + ni * 16 + lr) * 4;
              *(float*)(lds + rl * 1024 + (cb ^ ((rl & 7) << 4))) = acc[mi][ni][r];
            }
      }
      LGKM0; BAR;
#pragma unroll
      for (int it = 0; it < 16; ++it) {
        const int rl = w * 16 + it;
        f32x4 v = *(const f32x4*)(lds + rl * 1024 + ((l * 16) ^ ((rl & 7) << 4)));
        if (okc)
          *(f32x4*)(o + (size_t)(bm * 256 + h2 * 128 + rl) * NC + bn * 256 + l * 4) = v;
      }
    }
  }
}

// ---------------- causal depthwise conv (K=4) + bias + SiLU, bf16 in/out ------
__global__ __launch_bounds__(256) void conv_silu_kernel(const ushort_t* __restrict__ xbc,
                                                        const float* __restrict__ cw,
                                                        const float* __restrict__ cb,
                                                        ushort_t* __restrict__ out) {
  int idx = blockIdx.x * 256 + threadIdx.x;      // 4096*1536
  int c4 = (idx % 1536) << 2;
  int bt = idx / 1536;
  int t = bt & 2047;
  const ushort_t* base = xbc + (size_t)bt * 6272 + c4;
  f32x4 w0 = *(const f32x4*)&cw[(c4 + 0) * 4];
  f32x4 w1 = *(const f32x4*)&cw[(c4 + 1) * 4];
  f32x4 w2 = *(const f32x4*)&cw[(c4 + 2) * 4];
  f32x4 w3 = *(const f32x4*)&cw[(c4 + 3) * 4];
  f32x4 acc = *(const f32x4*)&cb[c4];
#pragma unroll
  for (int i = 0; i < 4; ++i) {
    int dt_ = i - 3;
    if (t + dt_ >= 0) {
      u16x4 xv = *(const u16x4*)(base + (ptrdiff_t)dt_ * 6272);
      acc.x += bf2f(xv.x) * w0[i];
      acc.y += bf2f(xv.y) * w1[i];
      acc.z += bf2f(xv.z) * w2[i];
      acc.w += bf2f(xv.w) * w3[i];
    }
  }
  u16x4 o;
  o.x = f2bf(siluf(acc.x)); o.y = f2bf(siluf(acc.y));
  o.z = f2bf(siluf(acc.z)); o.w = f2bf(siluf(acc.w));
  *(u16x4*)(out + (size_t)bt * 6144 + c4) = o;
}

// ---------------- dt: softplus + exp(A*dt), layout [H][2][BT] f32 -------------
__global__ __launch_bounds__(256) void dt_kernel(const ushort_t* __restrict__ xbc,
                                                 const float* __restrict__ dt_bias,
                                                 const float* __restrict__ Avec,
                                                 float* __restrict__ dtA) {
  int idx = blockIdx.x * 256 + threadIdx.x;      // 64*4096
  int h = idx >> 12, bt = idx & 4095;
  float v = bf2f(xbc[(size_t)bt * 6272 + 6144 + h]) + dt_bias[h];
  float sp = fmaxf(v, 0.f) + log1pf(expf(-fabsf(v)));
  float ab = expf(Avec[h] * sp);
  dtA[(h << 13) + bt] = sp;
  dtA[(h << 13) + 4096 + bt] = ab;
}

// ---------------- SSD chunk kernel (R13 version, unchanged) -------------------
__global__ __launch_bounds__(256) void ssd_kernel(const ushort_t* __restrict__ conv,
                                                  const float* __restrict__ dtA,
                                                  const float* __restrict__ Dvec,
                                                  const float* __restrict__ Avec,
                                                  ushort_t* __restrict__ yssm,
                                                  ushort_t* __restrict__ hst,
                                                  float* __restrict__ abprod) {
  const int bid = blockIdx.x;
  const int ck = bid & 7;
  const int h = (bid >> 3) & 63;
  const int b = bid >> 9;
  const int g = h >> 3;
  const int tid = threadIdx.x;
  const int lane = tid & 63;
  const int wv = tid >> 6;
  const int lr = lane & 15, lk = lane >> 4;
  const int btb = (b << 11) + (ck << 8);

  __shared__ __align__(16) unsigned char ldsb[69648];
  float* csL = (float*)(ldsb + 65536);
  float* dtL = (float*)(ldsb + 66560);
  float* wL  = (float*)(ldsb + 67584);
  float* l2L = (float*)(ldsb + 68608);
  float* wsum = (float*)(ldsb + 69632);

  const float Ah = Avec[h];
  const float Dh = Dvec[h];
  const float AhL2 = Ah * 1.44269504f;

  // ---- Ph0: inclusive cumsum of dt ----
  float dv = dtA[(h << 13) + btb + tid];
  float s = dv;
#pragma unroll
  for (int off = 1; off < 64; off <<= 1) {
    float t = __shfl_up(s, off, 64);
    if (lane >= off) s += t;
  }
  if (lane == 63) wsum[wv] = s;
  __syncthreads();
  float basev = 0.f;
  for (int i = 0; i < wv; ++i) basev += wsum[i];
  const float csv = basev + s;
  csL[tid] = csv;
  dtL[tid] = dv;
  l2L[tid] = AhL2 * csv;
  __syncthreads();
  const float cstot = csL[255];
  wL[tid] = dv * fexp2(AhL2 * (cstot - csv));
  if (tid == 0) abprod[((b << 6) + h) * 8 + ck] = expf(Ah * cstot);

  // ---- Ph1: XT build via coalesced column gather + vectorized writes ----
  const ushort_t* Xg = conv + (size_t)btb * 6144 + (h << 6);
  {
    const int p = lane;
#pragma unroll
    for (int rep = 0; rep < 8; ++rep) {
      const int t0 = (rep * 4 + wv) << 3;
      u16x8 v;
#pragma unroll
      for (int k = 0; k < 8; ++k) v[k] = Xg[(size_t)(t0 + k) * 6144 + p];
      *(u16x8*)(ldsb + p * 512 + ((t0 * 2) ^ ((p & 15) << 4))) = v;
    }
  }
  __syncthreads();   // XT + wL visible

  // ---- Ph2: hst = XT * BwT^T, t in two halves of 128 (BwT in scratch) ----
  const ushort_t* Bg = conv + (size_t)btb * 6144 + 4096 + (g << 7);
  f32x4 hacc[4][2] = {};
  for (int th = 0; th < 2; ++th) {
#pragma unroll
    for (int rep = 0; rep < 8; ++rep) {
      const int n = ((rep & 1) << 6) | lane;
      const int tl0 = ((rep >> 1) * 4 + wv) << 3;        // within-half t
      const int t0 = th * 128 + tl0;
      u16x8 v;
#pragma unroll
      for (int k = 0; k < 8; ++k)
        v[k] = f2bf(bf2f(Bg[(size_t)(t0 + k) * 6144 + n]) * wL[t0 + k]);
      *(u16x8*)(ldsb + 32768 + n * 256 + ((tl0 * 2) ^ ((n & 15) << 4))) = v;
    }
    __syncthreads();
#pragma unroll
    for (int tc = 0; tc < 4; ++tc) {
      bf16x8 a4[4], b2[2];
#pragma unroll
      for (int pf = 0; pf < 4; ++pf) {
        const int p = pf * 16 + lr;
        a4[pf] = *(const bf16x8*)(ldsb + p * 512 +
                                  (((th * 128 + tc * 32 + lk * 8) * 2) ^ ((p & 15) << 4)));
      }
#pragma unroll
      for (int nf = 0; nf < 2; ++nf) {
        const int n = wv * 32 + nf * 16 + lr;
        b2[nf] = *(const bf16x8*)(ldsb + 32768 + n * 256 +
                                  (((tc * 32 + lk * 8) * 2) ^ ((n & 15) << 4)));
      }
#pragma unroll
      for (int pf = 0; pf < 4; ++pf)
#pragma unroll
        for (int nf = 0; nf < 2; ++nf)
          hacc[pf][nf] = __builtin_amdgcn_mfma_f32_16x16x32_bf16(a4[pf], b2[nf],
                                                                 hacc[pf][nf], 0, 0, 0);
    }
    __syncthreads();   // scratch free before next half / Ph3
  }
  // write hst (layout identical to prior rounds)
#pragma unroll
  for (int pf = 0; pf < 4; ++pf)
#pragma unroll
    for (int nf = 0; nf < 2; ++nf)
#pragma unroll
      for (int r = 0; r < 4; ++r) {
        int p = pf * 16 + (lk << 2) + r;
        int n = wv * 32 + nf * 16 + lr;
        hst[((size_t)((b << 10) | (h << 4) | ((p >> 5) << 3) | ck)) * 4096 +
            (size_t)(p & 31) * 128 + n] = f2bf(hacc[pf][nf][r]);
      }

  // ---- Ph3: per 64-row block: S -> mask -> P -> Y^T ----
  const ushort_t* Cg = conv + (size_t)btb * 6144 + 5120 + (g << 7);
  for (int rb = 0; rb < 4; ++rb) {
    const int i0 = rb << 6;
    f32x4 sacc[4][4] = {};
#pragma unroll
    for (int kk = 0; kk < 4; ++kk) {
      bf16x8 ca[4], bb[4];
#pragma unroll
      for (int ifr = 0; ifr < 4; ++ifr)
        ca[ifr] = *(const bf16x8*)(Cg + (size_t)(i0 + ifr * 16 + lr) * 6144 + kk * 32 + lk * 8);
#pragma unroll
      for (int jf = 0; jf < 4; ++jf)
        bb[jf] = *(const bf16x8*)(Bg + (size_t)(wv * 64 + jf * 16 + lr) * 6144 + kk * 32 + lk * 8);
#pragma unroll
      for (int ifr = 0; ifr < 4; ++ifr)
#pragma unroll
        for (int jf = 0; jf < 4; ++jf)
          sacc[ifr][jf] = __builtin_amdgcn_mfma_f32_16x16x32_bf16(ca[ifr], bb[jf],
                                                                  sacc[ifr][jf], 0, 0, 0);
    }
    // mask + write P (swz (il&15)<<4). Decay via single-instr exp2.
#pragma unroll
    for (int ifr = 0; ifr < 4; ++ifr) {
      const int ibmax = i0 + ifr * 16 + 15;
#pragma unroll
      for (int jf = 0; jf < 4; ++jf) {
        const int jbmin = wv * 64 + jf * 16;          // wave-uniform
        const int j = jbmin + lr;
        if (jbmin > ibmax) {
#pragma unroll
          for (int r = 0; r < 4; ++r) {
            int il = ifr * 16 + (lk << 2) + r;
            *(ushort_t*)(ldsb + 32768 + il * 512 + ((j * 2) ^ ((il & 15) << 4))) = 0;
          }
        } else {
          const float dtj = dtL[j];
          const float l2j = l2L[j];
#pragma unroll
          for (int r = 0; r < 4; ++r) {
            int il = ifr * 16 + (lk << 2) + r;
            int ig = i0 + il;
            float val = 0.f;
            if (j <= ig) val = sacc[ifr][jf][r] * dtj * fexp2(l2L[ig] - l2j);
            *(ushort_t*)(ldsb + 32768 + il * 512 + ((j * 2) ^ ((il & 15) << 4))) = f2bf(val);
          }
        }
      }
    }
    __syncthreads();
    // Y^T[p][i] = sum_j XT[p][j] * P[i][j]
    f32x4 yacc[4] = {};
    const int ilB = wv * 16 + lr;
#pragma unroll
    for (int ks = 0; ks < 8; ++ks) {
      bf16x8 pb = *(const bf16x8*)(ldsb + 32768 + ilB * 512 +
                                   (((ks * 32 + lk * 8) * 2) ^ ((ilB & 15) << 4)));
#pragma unroll
      for (int pf = 0; pf < 4; ++pf) {
        const int p = pf * 16 + lr;
        bf16x8 pa = *(const bf16x8*)(ldsb + p * 512 +
                                     (((ks * 32 + lk * 8) * 2) ^ ((p & 15) << 4)));
        yacc[pf] = __builtin_amdgcn_mfma_f32_16x16x32_bf16(pa, pb, yacc[pf], 0, 0, 0);
      }
    }
    // epilogue: + D*x, write yssm
    const int irow = i0 + wv * 16 + lr;
    const size_t ybase = (size_t)(btb + irow) * 4096 + (h << 6);
#pragma unroll
    for (int pf = 0; pf < 4; ++pf) {
      u16x4 o;
#pragma unroll
      for (int r = 0; r < 4; ++r) {
        int p = pf * 16 + (lk << 2) + r;
        float xv = bf2f(*(const ushort_t*)(ldsb + p * 512 +
                                           ((irow * 2) ^ ((p & 15) << 4))));
        o[r] = f2bf(yacc[pf][r] + Dh * xv);
      }
      *(u16x4*)(yssm + ybase + pf * 16 + (lk << 2)) = o;
    }
    __syncthreads();   // protect P before next rb overwrites it
  }
}

// ---------------- combine: prefix over chunk states (in place) ----------------
__global__ __launch_bounds__(256) void combine_kernel(ushort_t* __restrict__ hst,
                                                      const float* __restrict__ abprod) {
  const int bid = blockIdx.x;
  const int bh = bid >> 1;
  const int tid = threadIdx.x;
  const size_t base = (size_t)bid * 8 * 4096 + tid * 16;
  float hrun[16];
#pragma unroll
  for (int e = 0; e < 16; ++e) hrun[e] = 0.f;
  for (int c = 0; c < 8; ++c) {
    const size_t p = base + (size_t)c * 4096;
    u16x8 v0 = *(const u16x8*)&hst[p];
    u16x8 v1 = *(const u16x8*)&hst[p + 8];
    float ab = abprod[bh * 8 + c];
    u16x8 w0, w1;
#pragma unroll
    for (int e = 0; e < 8; ++e) { w0[e] = f2bf(hrun[e]); w1[e] = f2bf(hrun[8 + e]); }
    *(u16x8*)&hst[p] = w0;
    *(u16x8*)&hst[p + 8] = w1;
#pragma unroll
    for (int e = 0; e < 8; ++e) {
      hrun[e] = ab * hrun[e] + bf2f(v0[e]);
      hrun[8 + e] = ab * hrun[8 + e] + bf2f(v1[e]);
    }
  }
}

// ---------------- correction: yssm += pd[t] * (C_t . H_init) ------------------
__global__ __launch_bounds__(256) void correct_kernel(const ushort_t* __restrict__ conv,
                                                      const float* __restrict__ dtA,
                                                      const float* __restrict__ Avec,
                                                      const ushort_t* __restrict__ hst,
                                                      ushort_t* __restrict__ yssm) {
  const int bid = blockIdx.x;
  const int ck = bid & 7;
  const int h = (bid >> 3) & 63;
  const int b = bid >> 9;
  const int g = h >> 3;
  const int tid = threadIdx.x;
  const int lane = tid & 63;
  const int w = tid >> 6;
  const int lr = lane & 15, lk = lane >> 4;
  const int btb = (b << 11) + (ck << 8);

  __shared__ float pdl[256];
  __shared__ float wsum[4];
  float s = dtA[(h << 13) + btb + tid];
#pragma unroll
  for (int off = 1; off < 64; off <<= 1) {
    float t = __shfl_up(s, off, 64);
    if (lane >= off) s += t;
  }
  if (lane == 63) wsum[w] = s;
  __syncthreads();
  float basev = 0.f;
  for (int i = 0; i < w; ++i) basev += wsum[i];
  pdl[tid] = expf(Avec[h] * (basev + s));
  __syncthreads();

  const ushort_t* Cc = conv + (size_t)btb * 6144 + 5120 + (g << 7);
  const size_t hb0 = ((size_t)((b << 10) | (h << 4) | (0 << 3) | ck)) * 4096;
  const size_t hb1 = ((size_t)((b << 10) | (h << 4) | (1 << 3) | ck)) * 4096;

  f32x4 acc[4][4] = {};
#pragma unroll
  for (int kk = 0; kk < 4; ++kk) {
    const int k0 = kk * 32 + lk * 8;
    bf16x8 afr[4], bfr[4];
#pragma unroll
    for (int mf = 0; mf < 4; ++mf) {
      const int t = w * 64 + mf * 16 + lr;
      afr[mf] = *(const bf16x8*)(Cc + (size_t)t * 6144 + k0);
    }
#pragma unroll
    for (int nf = 0; nf < 4; ++nf) {
      const int p = nf * 16 + lr;
      const size_t hb = (p < 32) ? hb0 : hb1;
      bfr[nf] = *(const bf16x8*)(hst + hb + (size_t)(p & 31) * 128 + k0);
    }
#pragma unroll
    for (int mf = 0; mf < 4; ++mf)
#pragma unroll
      for (int nf = 0; nf < 4; ++nf)
        acc[mf][nf] = __builtin_amdgcn_mfma_f32_16x16x32_bf16(afr[mf], bfr[nf],
                                                              acc[mf][nf], 0, 0, 0);
  }

#pragma unroll
  for (int mf = 0; mf < 4; ++mf) {
#pragma unroll
    for (int r = 0; r < 4; ++r) {
      const int row = w * 64 + mf * 16 + (lk << 2) + r;
      const float pd = pdl[row];
      const size_t yrow = (size_t)(btb + row) * 4096 + (h << 6);
#pragma unroll
      for (int nf = 0; nf < 4; ++nf) {
        const int p = nf * 16 + lr;
        const size_t idx = yrow + p;
        yssm[idx] = f2bf(bf2f(yssm[idx]) + pd * acc[mf][nf][r]);
      }
    }
  }
}

// ---------------- gate * silu + RMSNorm -> bf16 -------------------------------
__global__ __launch_bounds__(256) void norm_kernel(const ushort_t* __restrict__ yssm,
                                                   const ushort_t* __restrict__ gate,
                                                   const float* __restrict__ nw,
                                                   ushort_t* __restrict__ out) {
  const int bt = blockIdx.x;
  const int tid = threadIdx.x;
  const ushort_t* y = yssm + (size_t)bt * 4096;
  const ushort_t* gt = gate + (size_t)bt * 4096;
  float vals[16];
  float ss = 0.f;
#pragma unroll
  for (int j = 0; j < 4; ++j) {
    int o = (tid + j * 256) << 2;
    u16x4 yv = *(const u16x4*)(y + o);
    u16x4 gv = *(const u16x4*)(gt + o);
#pragma unroll
    for (int e = 0; e < 4; ++e) {
      float v = bf2f(yv[e]) * siluf(bf2f(gv[e]));
      vals[j * 4 + e] = v;
      ss += v * v;
    }
  }
#pragma unroll
  for (int m = 1; m <= 32; m <<= 1) ss += __shfl_xor(ss, m, 64);
  __shared__ float red[4];
  if ((tid & 63) == 0) red[tid >> 6] = ss;
  __syncthreads();
  ss = red[0] + red[1] + red[2] + red[3];
  const float sc = rsqrtf(ss * (1.f / 4096.f) + 1e-5f);
#pragma unroll
  for (int j = 0; j < 4; ++j) {
    int o = (tid + j * 256) << 2;
    f32x4 wv = *(const f32x4*)(nw + o);
    u16x4 ov;
    ov.x = f2bf(vals[j * 4 + 0] * sc * wv.x);
    ov.y = f2bf(vals[j * 4 + 1] * sc * wv.y);
    ov.z = f2bf(vals[j * 4 + 2] * sc * wv.z);
    ov.w = f2bf(vals[j * 4 + 3] * sc * wv.w);
    *(u16x4*)(out + (size_t)bt * 4096 + o) = ov;
  }
}

// ------------------------------------------------------------------------------
extern "C" void kernel_launch(void* const* d_in, const int* in_sizes, int n_in,
                              void* d_out, int out_size, void* d_ws, size_t ws_size,
                              hipStream_t stream) {
  const float* hidden  = (const float*)d_in[0];
  const float* w_in    = (const float*)d_in[1];
  const float* conv_w  = (const float*)d_in[2];
  const float* conv_b  = (const float*)d_in[3];
  const float* Avec    = (const float*)d_in[4];
  const float* Dvec    = (const float*)d_in[5];
  const float* dt_bias = (const float*)d_in[6];
  const float* nw      = (const float*)d_in[7];
  const float* w_out   = (const float*)d_in[8];
  float* out = (float*)d_out;

  char* ws = (char*)d_ws;
  // Region map (total 162,693,120 B) — unchanged since R4.
  ushort_t* Xbf   = (ushort_t*)(ws);
  ushort_t* W1bf  = (ushort_t*)(ws + 22020096);
  ushort_t* gate  = (ushort_t*)(ws + 77758464);
  ushort_t* xbc   = (ushort_t*)(ws + 111312896);
  ushort_t* W2bf  = Xbf;
  ushort_t* convb = W1bf;
  float*    dtA   = (float*)(ws + 22020096 + 50331648);
  float*    abprod= (float*)(ws + 22020096 + 52428800);
  ushort_t* yssm  = xbc;
  ushort_t* hst   = (ushort_t*)(ws + 111312896 + 33554432);
  ushort_t* ynorm = convb;
  const size_t NEED = 162693120;
  if (NEED > ws_size) {
    fill_kernel<<<4, 256, 0, stream>>>(out, 12345.0f, 1024);   // sentinel: ws too small
    return;
  }

  cvt_bf16_kernel<<<10752, 256, 0, stream>>>(hidden, Xbf, 2752512, 2752512);
  cvt_bf16_kernel<<<27216, 256, 0, stream>>>(w_in, W1bf, 6924288, 6967296);
  gemm8_kernel<0><<<dim3(16, 41), 512, 0, stream>>>(Xbf, W1bf, gate, xbc,
                                                    2688, 10368, 10304, 21);
  cvt_bf16_kernel<<<10752, 256, 0, stream>>>(w_out, W2bf, 2752512, 2752512);
  conv_silu_kernel<<<24576, 256, 0, stream>>>(xbc, conv_w, conv_b, convb);
  dt_kernel<<<1024, 256, 0, stream>>>(xbc, dt_bias, Avec, dtA);
  ssd_kernel<<<1024, 256, 0, stream>>>(convb, dtA, Dvec, Avec, yssm, hst, abprod);
  combine_kernel<<<256, 256, 0, stream>>>(hst, abprod);
  correct_kernel<<<1024, 256, 0, stream>>>(convb, dtA, Avec, hst, yssm);
  norm_kernel<<<4096, 256, 0, stream>>>(yssm, gate, nw, ynorm);
  gemm8_kernel<1><<<dim3(16, 11), 512, 0, stream>>>(ynorm, W2bf, out, nullptr,
                                                    4096, 2688, 2688, 32);
}